// Round 6
// baseline (985.548 us; speedup 1.0000x reference)
//
#include <hip/hip_runtime.h>
#include <hip/hip_bf16.h>

// Problem constants (fixed by reference)
#define Nn     20000
#define Ee     240000
#define Gg     64
#define Ff     768
#define H1c    128
#define PEc    32
#define Dd     160      // H1 + PE
#define HEADSc 5
#define HCc    800      // HEADS * D
#define H2c    128
#define OUTc   16
#define ETot   (Ee + Nn)  // edges + self loops = 260000
#define NEG_SLOPE_F 0.2f

typedef short bf16x8 __attribute__((ext_vector_type(8)));
typedef float f32x4 __attribute__((ext_vector_type(4)));
typedef unsigned int u32;

// ---- bf16 split helpers (round-to-nearest-even) ----
__device__ __forceinline__ unsigned short bf_hi_rn(float v) {
    unsigned int u = __float_as_uint(v);
    return (unsigned short)((u + 0x7FFFu + ((u >> 16) & 1u)) >> 16);
}
__device__ __forceinline__ void bsplit(float v, unsigned short& h, unsigned short& l) {
    unsigned short hh = bf_hi_rn(v);
    float hf = __uint_as_float(((unsigned int)hh) << 16);
    l = bf_hi_rn(v - hf);
    h = hh;
}

// async global->LDS, 16 B per lane; LDS dest = wave-uniform base + lane*16
__device__ __forceinline__ void gl_lds16(const unsigned short* g, unsigned short* l) {
    __builtin_amdgcn_global_load_lds(
        (const __attribute__((address_space(1))) u32*)g,
        (__attribute__((address_space(3))) u32*)l, 16, 0, 0);
}

// ---------------------------------------------------------------------------
// Split fp32 array -> bf16 hi/lo arrays (same layout), vectorized by 4
// ---------------------------------------------------------------------------
__global__ void asplit_kernel(const float* __restrict__ A, unsigned short* __restrict__ Ah,
                              unsigned short* __restrict__ Al, int total4) {
    int i = blockIdx.x * 256 + threadIdx.x;
    if (i < total4) {
        float4 v = ((const float4*)A)[i];
        ushort4 h4, l4;
        bsplit(v.x, h4.x, l4.x);
        bsplit(v.y, h4.y, l4.y);
        bsplit(v.z, h4.z, l4.z);
        bsplit(v.w, h4.w, l4.w);
        ((ushort4*)Ah)[i] = h4;
        ((ushort4*)Al)[i] = l4;
    }
}

// Weight transpose + split: W[K][N] fp32 -> Wh/Wl[N][K] bf16
__global__ void wsplit_kernel(const float* __restrict__ W, unsigned short* __restrict__ Wh,
                              unsigned short* __restrict__ Wl, int K, int N) {
    int i = blockIdx.x * 256 + threadIdx.x;
    if (i < K * N) {
        int k = i / N, n = i % N;
        unsigned short h, l;
        bsplit(W[i], h, l);
        Wh[(size_t)n * K + k] = h;
        Wl[(size_t)n * K + k] = l;
    }
}

// ---------------------------------------------------------------------------
// bf16x3 MFMA GEMM, templated tile (BMxBN in {128x128, 64x64}).
// ---------------------------------------------------------------------------
#define KCHUNK 32

template<int ROWS>
__device__ __forceinline__ void stage_tile(const unsigned short* __restrict__ gsrc, int ld,
                                           int row0, int maxRow, int k0,
                                           unsigned short* lbuf, int wave, int lane) {
    #pragma unroll
    for (int p = 0; p < ROWS / 64; ++p) {
        int rb = wave * 16 + p * 64;
        int r = rb + (lane >> 2);
        int gr = min(row0 + r, maxRow);
        const unsigned short* g = gsrc + (size_t)gr * ld + k0 + (lane & 3) * 8;
        gl_lds16(g, lbuf + rb * 32);
    }
}

template<int BM, int BN, int OUT_MODE>
__global__ __launch_bounds__(256)
void gemm3_kernel(const unsigned short* __restrict__ Ah, const unsigned short* __restrict__ Al,
                  const unsigned short* __restrict__ Bh, const unsigned short* __restrict__ Bl,
                  const float* __restrict__ bias, float* __restrict__ C,
                  unsigned short* __restrict__ Ch, unsigned short* __restrict__ Cl,
                  int M, int N, int K, int lda, int ldc, int relu) {
    constexpr int TM = BM / 32;
    constexpr int TN = BN / 32;
    __shared__ __attribute__((aligned(16))) unsigned short As_h[BM * 32];
    __shared__ __attribute__((aligned(16))) unsigned short As_l[BM * 32];
    __shared__ __attribute__((aligned(16))) unsigned short Bs_h[BN * 32];
    __shared__ __attribute__((aligned(16))) unsigned short Bs_l[BN * 32];

    int tid = threadIdx.x;
    int m0 = blockIdx.x * BM, n0 = blockIdx.y * BN;
    int wave = tid >> 6, lane = tid & 63;
    int wm = (wave >> 1) * (16 * TM);
    int wn = (wave & 1) * (16 * TN);
    int fr = lane & 15;
    int fq = (lane >> 4) * 8;

    f32x4 acc[TM][TN] = {};

    for (int k0 = 0; k0 < K; k0 += KCHUNK) {
        stage_tile<BM>(Ah, lda, m0, M - 1, k0, As_h, wave, lane);
        stage_tile<BM>(Al, lda, m0, M - 1, k0, As_l, wave, lane);
        stage_tile<BN>(Bh, K,   n0, N - 1, k0, Bs_h, wave, lane);
        stage_tile<BN>(Bl, K,   n0, N - 1, k0, Bs_l, wave, lane);
        __syncthreads();

        bf16x8 a_h[TM], a_l[TM], b_h[TN], b_l[TN];
        #pragma unroll
        for (int i = 0; i < TM; ++i) {
            a_h[i] = *(const bf16x8*)&As_h[(wm + i * 16 + fr) * 32 + fq];
            a_l[i] = *(const bf16x8*)&As_l[(wm + i * 16 + fr) * 32 + fq];
        }
        #pragma unroll
        for (int j = 0; j < TN; ++j) {
            b_h[j] = *(const bf16x8*)&Bs_h[(wn + j * 16 + fr) * 32 + fq];
            b_l[j] = *(const bf16x8*)&Bs_l[(wn + j * 16 + fr) * 32 + fq];
        }
        #pragma unroll
        for (int j = 0; j < TN; ++j) {
            #pragma unroll
            for (int i = 0; i < TM; ++i) {
                acc[i][j] = __builtin_amdgcn_mfma_f32_16x16x32_bf16(a_h[i], b_h[j], acc[i][j], 0, 0, 0);
                acc[i][j] = __builtin_amdgcn_mfma_f32_16x16x32_bf16(a_h[i], b_l[j], acc[i][j], 0, 0, 0);
                acc[i][j] = __builtin_amdgcn_mfma_f32_16x16x32_bf16(a_l[i], b_h[j], acc[i][j], 0, 0, 0);
            }
        }
        __syncthreads();
    }

    int cr = (lane >> 4) * 4, cc = lane & 15;
    #pragma unroll
    for (int i = 0; i < TM; ++i) {
        #pragma unroll
        for (int j = 0; j < TN; ++j) {
            int c = n0 + wn + j * 16 + cc;
            if (c >= N) continue;
            float bv = bias ? bias[c] : 0.f;
            #pragma unroll
            for (int reg = 0; reg < 4; ++reg) {
                int r = m0 + wm + i * 16 + cr + reg;
                if (r >= M) continue;
                float v = acc[i][j][reg] + bv;
                if (relu) v = fmaxf(v, 0.f);
                if (OUT_MODE == 0) {
                    C[(size_t)r * ldc + c] = v;
                } else {
                    unsigned short hh, ll;
                    bsplit(v, hh, ll);
                    Ch[(size_t)r * ldc + c] = hh;
                    Cl[(size_t)r * ldc + c] = ll;
                }
            }
        }
    }
}

// copy pe_enc into h splits cols [128:160)
__global__ void pe_copy_kernel(const float* __restrict__ pe, unsigned short* __restrict__ hh,
                               unsigned short* __restrict__ hl) {
    int i = blockIdx.x * 256 + threadIdx.x;
    if (i < Nn * PEc) {
        int n = i / PEc, j = i % PEc;
        unsigned short h, l;
        bsplit(pe[i], h, l);
        hh[(size_t)n * Dd + H1c + j] = h;
        hl[(size_t)n * Dd + H1c + j] = l;
    }
}

// count in-degree (real edges only)
__global__ void count_kernel(const int* __restrict__ eidx, int* __restrict__ cnt) {
    int e = blockIdx.x * 256 + threadIdx.x;
    if (e < Ee) atomicAdd(&cnt[eidx[Ee + e]], 1);
}

// ---- multi-block exclusive scan over (cnt[i]+1) ----
#define NBLK 79  // ceil(20000/256)
__global__ void scan1_kernel(const int* __restrict__ cnt, int* __restrict__ off,
                             int* __restrict__ bsum) {
    __shared__ int sh[256];
    int t = threadIdx.x, i = blockIdx.x * 256 + t;
    int v = (i < Nn) ? (cnt[i] + 1) : 0;
    sh[t] = v;
    __syncthreads();
    for (int ofs = 1; ofs < 256; ofs <<= 1) {
        int add = (t >= ofs) ? sh[t - ofs] : 0;
        __syncthreads();
        sh[t] += add;
        __syncthreads();
    }
    if (i < Nn) off[i] = sh[t] - v;
    if (t == 255) bsum[blockIdx.x] = sh[255];
}
__global__ void scan2_kernel(int* __restrict__ bsum) {
    if (threadIdx.x == 0) {
        int acc = 0;
        for (int b = 0; b < NBLK; ++b) { int v = bsum[b]; bsum[b] = acc; acc += v; }
    }
}
__global__ void scan3_kernel(const int* __restrict__ cnt, int* __restrict__ off,
                             int* __restrict__ nxt, float* __restrict__ dinv,
                             const int* __restrict__ bsum) {
    int i = blockIdx.x * 256 + threadIdx.x;
    if (i < Nn) {
        int o = off[i] + bsum[blockIdx.x];
        off[i] = o;
        nxt[i] = o;
        dinv[i] = rsqrtf((float)(cnt[i] + 1));
    }
    if (i == 0) off[Nn] = ETot;
}

// scatter edges (and self loops) into CSR by dst
__global__ void scatter_kernel(const int* __restrict__ eidx, int* __restrict__ nxt,
                               int* __restrict__ elist, int* __restrict__ edst) {
    int e = blockIdx.x * 256 + threadIdx.x;
    if (e < ETot) {
        int s, d;
        if (e < Ee) { s = eidx[e]; d = eidx[Ee + e]; }
        else        { s = e - Ee; d = s; }
        int slot = atomicAdd(&nxt[d], 1);
        elist[slot] = s;
        edst[slot] = d;
    }
}

// ---------------------------------------------------------------------------
// FUSED GATv2, chunk-parallel: per 32-edge chunk
//   A) half-wave per edge computes its 5 head scores (wave shuffles only)
//   B) 5 threads: chunk softmax update, all weights relative to chunk max
//   C) 200 threads: acc = acc*scale + sum_e w_e * xl[src_e]  (L2-hot re-read)
// ---------------------------------------------------------------------------
#define FCH 32
__global__ __launch_bounds__(256)
void fused_gat_kernel(const float* __restrict__ xl, const float* __restrict__ xr,
                      const float* __restrict__ att, const int* __restrict__ elist,
                      const int* __restrict__ off, const float* __restrict__ gat_bias,
                      unsigned short* __restrict__ g1h, unsigned short* __restrict__ g1l) {
    int d = blockIdx.x;
    int t = threadIdx.x;
    int wave = t >> 6, lane = t & 63, half = lane >> 5, j = lane & 31;
    __shared__ float sh_sc[FCH][HEADSc];
    __shared__ float sh_w[FCH][HEADSc];
    __shared__ float sh_scale[HEADSc], sh_m[HEADSc], sh_den[HEADSc];
    __shared__ int sh_src[FCH];
    int e0 = off[d], e1 = off[d + 1];
    int cnt = e1 - e0;
    bool act = t < 200;
    int hd = act ? (t / 40) : 0;

    // att fragments (half-wave score layout)
    const float4* at4 = (const float4*)att;
    bool tail = (j < 8);
    float4 ta[HEADSc], tb[HEADSc];
    #pragma unroll
    for (int h = 0; h < HEADSc; ++h) ta[h] = at4[h * 40 + j];
    if (tail) {
        #pragma unroll
        for (int h = 0; h < HEADSc; ++h) tb[h] = at4[h * 40 + 32 + j];
    }
    const float4* prow = (const float4*)(xr + (size_t)d * HCc);

    if (t < HEADSc) { sh_m[t] = -1e30f; sh_den[t] = 0.f; }
    float4 acc = {0.f, 0.f, 0.f, 0.f};

    for (int base = 0; base < cnt; base += FCH) {
        int nc = min(FCH, cnt - base);
        if (t < nc) sh_src[t] = elist[e0 + base + t];
        __syncthreads();
        // Phase A: parallel scores, half-wave per edge, strided by 8
        for (int el = wave * 2 + half; el < nc; el += 8) {
            const float4* pl = (const float4*)(xl + (size_t)sh_src[el] * HCc);
            #pragma unroll
            for (int h = 0; h < HEADSc; ++h) {
                float4 a = pl[h * 40 + j];
                float4 b = prow[h * 40 + j];
                float4 tt = ta[h];
                float m, lm, s = 0.f;
                m = a.x + b.x; lm = fmaxf(m, 0.2f * m); s = fmaf(lm, tt.x, s);
                m = a.y + b.y; lm = fmaxf(m, 0.2f * m); s = fmaf(lm, tt.y, s);
                m = a.z + b.z; lm = fmaxf(m, 0.2f * m); s = fmaf(lm, tt.z, s);
                m = a.w + b.w; lm = fmaxf(m, 0.2f * m); s = fmaf(lm, tt.w, s);
                if (tail) {
                    float4 a2 = pl[h * 40 + 32 + j];
                    float4 b2 = prow[h * 40 + 32 + j];
                    float4 t2 = tb[h];
                    m = a2.x + b2.x; lm = fmaxf(m, 0.2f * m); s = fmaf(lm, t2.x, s);
                    m = a2.y + b2.y; lm = fmaxf(m, 0.2f * m); s = fmaf(lm, t2.y, s);
                    m = a2.z + b2.z; lm = fmaxf(m, 0.2f * m); s = fmaf(lm, t2.z, s);
                    m = a2.w + b2.w; lm = fmaxf(m, 0.2f * m); s = fmaf(lm, t2.w, s);
                }
                #pragma unroll
                for (int ofs = 16; ofs >= 1; ofs >>= 1) s += __shfl_xor(s, ofs, 64);
                if (j == 0) sh_sc[el][h] = s;
            }
        }
        __syncthreads();
        // Phase B: chunk softmax update (per head)
        if (t < HEADSc) {
            float mo = sh_m[t];
            float mn = mo;
            for (int el = 0; el < nc; ++el) mn = fmaxf(mn, sh_sc[el][t]);
            float sc = __expf(mo - mn);
            float den = sh_den[t] * sc;
            for (int el = 0; el < nc; ++el) {
                float w = __expf(sh_sc[el][t] - mn);
                sh_w[el][t] = w;
                den += w;
            }
            sh_den[t] = den;
            sh_m[t] = mn;
            sh_scale[t] = sc;
        }
        __syncthreads();
        // Phase C: aggregation (re-read vl, L2-hot)
        if (act) {
            float sc = sh_scale[hd];
            acc.x *= sc; acc.y *= sc; acc.z *= sc; acc.w *= sc;
            for (int el = 0; el < nc; ++el) {
                float w = sh_w[el][hd];
                float4 v = ((const float4*)(xl + (size_t)sh_src[el] * HCc))[t];
                acc.x = fmaf(w, v.x, acc.x);
                acc.y = fmaf(w, v.y, acc.y);
                acc.z = fmaf(w, v.z, acc.z);
                acc.w = fmaf(w, v.w, acc.w);
            }
        }
        __syncthreads();
    }
    if (act) {
        float inv = 1.f / sh_den[hd];
        float4 bv = ((const float4*)gat_bias)[t];
        ushort4 oh, ol;
        float v;
        v = fmaxf(fmaf(acc.x, inv, bv.x), 0.f); bsplit(v, oh.x, ol.x);
        v = fmaxf(fmaf(acc.y, inv, bv.y), 0.f); bsplit(v, oh.y, ol.y);
        v = fmaxf(fmaf(acc.z, inv, bv.z), 0.f); bsplit(v, oh.z, ol.z);
        v = fmaxf(fmaf(acc.w, inv, bv.w), 0.f); bsplit(v, oh.w, ol.w);
        *(ushort4*)(g1h + (size_t)d * HCc + 4 * t) = oh;
        *(ushort4*)(g1l + (size_t)d * HCc + 4 * t) = ol;
    }
}

// GCN aggregate, float4 form: g2[d] = relu(dinv[d] * sum dinv[src]*hg[src] + b)
__global__ __launch_bounds__(256)
void gcn_kernel(const float* __restrict__ hg, const float* __restrict__ dinv,
                const int* __restrict__ elist, const int* __restrict__ off,
                const float* __restrict__ b_gcn, float* __restrict__ g2) {
    int d = blockIdx.x;
    int t = threadIdx.x;
    __shared__ int src_s[64];
    __shared__ float w_s[64];
    int e0 = off[d], e1 = off[d + 1];
    int cnt = e1 - e0;
    float di = dinv[d];
    float4 acc = {0.f, 0.f, 0.f, 0.f};
    for (int base = 0; base < cnt; base += 64) {
        int nc = min(64, cnt - base);
        if (t < nc) {
            int s = elist[e0 + base + t];
            src_s[t] = s;
            w_s[t] = dinv[s];
        }
        __syncthreads();
        if (t < 200) {
            for (int el = 0; el < nc; ++el) {
                const float4* p = (const float4*)(hg + (size_t)src_s[el] * HCc);
                float w = w_s[el];
                float4 v = p[t];
                acc.x = fmaf(w, v.x, acc.x);
                acc.y = fmaf(w, v.y, acc.y);
                acc.z = fmaf(w, v.z, acc.z);
                acc.w = fmaf(w, v.w, acc.w);
            }
        }
        __syncthreads();
    }
    if (t < 200) {
        float4 bv = ((const float4*)b_gcn)[t];
        float4 o;
        o.x = fmaxf(acc.x * di + bv.x, 0.f);
        o.y = fmaxf(acc.y * di + bv.y, 0.f);
        o.z = fmaxf(acc.z * di + bv.z, 0.f);
        o.w = fmaxf(acc.w * di + bv.w, 0.f);
        *(float4*)(g2 + (size_t)d * HCc + 4 * t) = o;
    }
}

// graph boundaries in sorted batch (lower bound per graph)
__global__ void bounds_kernel(const int* __restrict__ batch, int* __restrict__ starts) {
    int g = threadIdx.x;
    if (g <= Gg) {
        if (g == Gg) { starts[Gg] = Nn; return; }
        int lo = 0, hi = Nn;
        while (lo < hi) {
            int mid = (lo + hi) >> 1;
            if (batch[mid] < g) lo = mid + 1; else hi = mid;
        }
        starts[g] = lo;
    }
}

// ---- two-stage pool: node-sliced partials, then combine ----
#define PSL 4
__global__ __launch_bounds__(256)
void pool1_kernel(const float* __restrict__ g2, const float* __restrict__ fw,
                  const int* __restrict__ starts, float* __restrict__ pw,
                  float* __restrict__ pmean, float* __restrict__ pmax) {
    int g = blockIdx.x, s = blockIdx.y, t = threadIdx.x;
    int n0 = starts[g], n1 = starts[g + 1];
    int len = n1 - n0;
    int q0 = n0 + (int)(((long long)len * s) / PSL);
    int q1 = n0 + (int)(((long long)len * (s + 1)) / PSL);
    __shared__ float red[256];
    float wsum = 0.f;
    for (int n = q0 + t; n < q1; n += 256) wsum += fw[n];
    red[t] = wsum;
    __syncthreads();
    for (int ofs = 128; ofs > 0; ofs >>= 1) {
        if (t < ofs) red[t] += red[t + ofs];
        __syncthreads();
    }
    if (t == 0) pw[g * PSL + s] = red[0];
    if (t < 200) {
        float4 sum = {0.f, 0.f, 0.f, 0.f};
        float4 mx = {0.f, 0.f, 0.f, 0.f};
        for (int n = q0; n < q1; ++n) {
            float w = fw[n];
            float4 v = ((const float4*)(g2 + (size_t)n * HCc))[t];
            sum.x = fmaf(w, v.x, sum.x); sum.y = fmaf(w, v.y, sum.y);
            sum.z = fmaf(w, v.z, sum.z); sum.w = fmaf(w, v.w, sum.w);
            mx.x = fmaxf(mx.x, v.x); mx.y = fmaxf(mx.y, v.y);
            mx.z = fmaxf(mx.z, v.z); mx.w = fmaxf(mx.w, v.w);
        }
        size_t o = ((size_t)g * PSL + s) * HCc + 4 * t;
        *(float4*)(pmean + o) = sum;
        *(float4*)(pmax + o) = mx;
    }
}
__global__ __launch_bounds__(256)
void pool2_kernel(const float* __restrict__ pw, const float* __restrict__ pmean,
                  const float* __restrict__ pmax, float* __restrict__ gfeat) {
    int g = blockIdx.x, t = threadIdx.x;
    if (t >= 200) return;
    float wsg = 0.f;
    #pragma unroll
    for (int s = 0; s < PSL; ++s) wsg += pw[g * PSL + s];
    wsg = fmaxf(wsg, 1e-6f);
    float inv = 1.f / wsg;
    float4 sum = {0.f, 0.f, 0.f, 0.f};
    float4 mx = {0.f, 0.f, 0.f, 0.f};
    #pragma unroll
    for (int s = 0; s < PSL; ++s) {
        size_t o = ((size_t)g * PSL + s) * HCc + 4 * t;
        float4 a = *(const float4*)(pmean + o);
        float4 b = *(const float4*)(pmax + o);
        sum.x += a.x; sum.y += a.y; sum.z += a.z; sum.w += a.w;
        mx.x = fmaxf(mx.x, b.x); mx.y = fmaxf(mx.y, b.y);
        mx.z = fmaxf(mx.z, b.z); mx.w = fmaxf(mx.w, b.w);
    }
    float* gm = gfeat + (size_t)g * (2 * HCc);
    sum.x *= inv; sum.y *= inv; sum.z *= inv; sum.w *= inv;
    *(float4*)(gm + 4 * t) = sum;
    *(float4*)(gm + HCc + 4 * t) = mx;
}

// final MLP head: out = relu(relu(gfeat@W_fc + b_fc) @ W_out + b_out)
__global__ __launch_bounds__(128)
void head_kernel(const float* __restrict__ gfeat, const float* __restrict__ W_fc,
                 const float* __restrict__ b_fc, const float* __restrict__ W_out,
                 const float* __restrict__ b_out, float* __restrict__ out) {
    int g = blockIdx.x;
    int t = threadIdx.x;  // 128
    __shared__ float gf[2 * HCc];
    __shared__ float fc1[H2c];
    for (int i = t; i < 2 * HCc; i += 128) gf[i] = gfeat[(size_t)g * (2 * HCc) + i];
    __syncthreads();
    float a0 = 0.f, a1 = 0.f, a2 = 0.f, a3 = 0.f;
    for (int k = 0; k < 2 * HCc; k += 4) {
        a0 = fmaf(gf[k],     W_fc[(size_t)k * H2c + t], a0);
        a1 = fmaf(gf[k + 1], W_fc[(size_t)(k + 1) * H2c + t], a1);
        a2 = fmaf(gf[k + 2], W_fc[(size_t)(k + 2) * H2c + t], a2);
        a3 = fmaf(gf[k + 3], W_fc[(size_t)(k + 3) * H2c + t], a3);
    }
    fc1[t] = fmaxf(b_fc[t] + ((a0 + a1) + (a2 + a3)), 0.f);
    __syncthreads();
    if (t < OUTc) {
        float o = b_out[t];
        #pragma unroll 8
        for (int k = 0; k < H2c; ++k) o += fc1[k] * W_out[k * OUTc + t];
        out[g * OUTc + t] = fmaxf(o, 0.f);
    }
}

extern "C" void kernel_launch(void* const* d_in, const int* in_sizes, int n_in,
                              void* d_out, int out_size, void* d_ws, size_t ws_size,
                              hipStream_t stream) {
    (void)in_sizes; (void)n_in; (void)out_size; (void)ws_size;
    const float* x        = (const float*)d_in[0];
    const float* pe       = (const float*)d_in[1];
    const int*   eidx     = (const int*)d_in[2];
    const int*   batch    = (const int*)d_in[3];
    const float* fw       = (const float*)d_in[4];
    const float* W_pre    = (const float*)d_in[6];
    const float* b_pre    = (const float*)d_in[7];
    const float* W_l      = (const float*)d_in[8];
    const float* b_l      = (const float*)d_in[9];
    const float* W_r      = (const float*)d_in[10];
    const float* b_r      = (const float*)d_in[11];
    const float* att      = (const float*)d_in[12];
    const float* gat_bias = (const float*)d_in[13];
    const float* W_gcn    = (const float*)d_in[14];
    const float* b_gcn    = (const float*)d_in[15];
    const float* W_fc     = (const float*)d_in[16];
    const float* b_fc     = (const float*)d_in[17];
    const float* W_out    = (const float*)d_in[18];
    const float* b_out    = (const float*)d_in[19];
    float* out = (float*)d_out;

    // ---- workspace carving ----
    char* p = (char*)d_ws;
    auto alloc = [&](size_t bytes) {
        char* r = p;
        p += (bytes + 255) & ~(size_t)255;
        return r;
    };
    unsigned short* hh = (unsigned short*)alloc((size_t)Nn * Dd * 2 * 2);
    unsigned short* hl = hh + (size_t)Nn * Dd;
    float* bufA = (float*)alloc((size_t)Nn * HCc * 4);  // xl, later hg
    float* bufB = (float*)alloc((size_t)Nn * HCc * 4);  // xr, later g2
    float* bufC = (float*)alloc((size_t)Nn * HCc * 4);  // x splits, later g1 splits
    int*   cnt    = (int*)alloc((size_t)Nn * 4);
    int*   off    = (int*)alloc((size_t)(Nn + 1) * 4);
    int*   nxt    = (int*)alloc((size_t)Nn * 4);
    float* dinv   = (float*)alloc((size_t)Nn * 4);
    int*   elist  = (int*)alloc((size_t)ETot * 4);
    int*   edst   = (int*)alloc((size_t)ETot * 4);
    int*   starts = (int*)alloc((size_t)(Gg + 1) * 4);
    float* gfeat  = (float*)alloc((size_t)Gg * 2 * HCc * 4);
    int*   bsum   = (int*)alloc((size_t)NBLK * 4);
    float* pw     = (float*)alloc((size_t)Gg * PSL * 4);
    float* pmean  = (float*)alloc((size_t)Gg * PSL * HCc * 4);
    float* pmax   = (float*)alloc((size_t)Gg * PSL * HCc * 4);
    unsigned short* WpreTh = (unsigned short*)alloc((size_t)Ff * H1c * 2 * 2);
    unsigned short* WpreTl = WpreTh + (size_t)Ff * H1c;
    unsigned short* WlTh   = (unsigned short*)alloc((size_t)Dd * HCc * 2 * 2);
    unsigned short* WlTl   = WlTh + (size_t)Dd * HCc;
    unsigned short* WrTh   = (unsigned short*)alloc((size_t)Dd * HCc * 2 * 2);
    unsigned short* WrTl   = WrTh + (size_t)Dd * HCc;
    unsigned short* WgTh   = (unsigned short*)alloc((size_t)HCc * HCc * 2 * 2);
    unsigned short* WgTl   = WgTh + (size_t)HCc * HCc;

    // aliases (disjoint lifetimes within bufC)
    unsigned short* xh  = (unsigned short*)bufC;   // x splits: prep -> GEMM1
    unsigned short* xlo = xh + (size_t)Nn * Ff;
    unsigned short* g1h = (unsigned short*)bufC;   // g1 splits: fused agg -> GEMM4
    unsigned short* g1l = g1h + (size_t)Nn * HCc;

    // ---- CSR build ----
    hipMemsetAsync(cnt, 0, (size_t)Nn * 4, stream);
    count_kernel<<<(Ee + 255) / 256, 256, 0, stream>>>(eidx, cnt);
    scan1_kernel<<<NBLK, 256, 0, stream>>>(cnt, off, bsum);
    scan2_kernel<<<1, 64, 0, stream>>>(bsum);
    scan3_kernel<<<NBLK, 256, 0, stream>>>(cnt, off, nxt, dinv, bsum);
    scatter_kernel<<<(ETot + 255) / 256, 256, 0, stream>>>(eidx, nxt, elist, edst);

    // ---- splits ----
    asplit_kernel<<<(Nn * Ff / 4 + 255) / 256, 256, 0, stream>>>(x, xh, xlo, Nn * Ff / 4);
    wsplit_kernel<<<(Ff * H1c + 255) / 256, 256, 0, stream>>>(W_pre, WpreTh, WpreTl, Ff, H1c);
    wsplit_kernel<<<(Dd * HCc + 255) / 256, 256, 0, stream>>>(W_l, WlTh, WlTl, Dd, HCc);
    wsplit_kernel<<<(Dd * HCc + 255) / 256, 256, 0, stream>>>(W_r, WrTh, WrTl, Dd, HCc);
    wsplit_kernel<<<(HCc * HCc + 255) / 256, 256, 0, stream>>>(W_gcn, WgTh, WgTl, HCc, HCc);

    // ---- GEMM1 (64x64 tile, bigger grid): h = relu(x@W_pre+b) -> h splits ----
    {
        dim3 grid((Nn + 63) / 64, (H1c + 63) / 64);
        gemm3_kernel<64, 64, 1><<<grid, 256, 0, stream>>>(
            xh, xlo, WpreTh, WpreTl, b_pre, nullptr, hh, hl,
            Nn, H1c, Ff, Ff, Dd, 1);
    }
    pe_copy_kernel<<<(Nn * PEc + 255) / 256, 256, 0, stream>>>(pe, hh, hl);

    // ---- GEMM2/3: xl = h@W_l + b_l -> bufA ; xr = h@W_r + b_r -> bufB ----
    {
        dim3 grid((Nn + 127) / 128, (HCc + 127) / 128);
        gemm3_kernel<128, 128, 0><<<grid, 256, 0, stream>>>(
            hh, hl, WlTh, WlTl, b_l, bufA, nullptr, nullptr,
            Nn, HCc, Dd, Dd, HCc, 0);
        gemm3_kernel<128, 128, 0><<<grid, 256, 0, stream>>>(
            hh, hl, WrTh, WrTl, b_r, bufB, nullptr, nullptr,
            Nn, HCc, Dd, Dd, HCc, 0);
    }

    // ---- FUSED GATv2 (chunk-parallel) -> g1 (bufC) ----
    fused_gat_kernel<<<Nn, 256, 0, stream>>>(bufA, bufB, att, elist, off,
                                             gat_bias, g1h, g1l);

    // ---- GEMM4: hg = g1 @ W_gcn -> bufA (xl dead) ----
    {
        dim3 grid((Nn + 127) / 128, (HCc + 127) / 128);
        gemm3_kernel<128, 128, 0><<<grid, 256, 0, stream>>>(
            g1h, g1l, WgTh, WgTl, nullptr, bufA, nullptr, nullptr,
            Nn, HCc, HCc, HCc, HCc, 0);
    }
    // ---- GCN aggregate -> g2 (bufB, xr dead) ----
    gcn_kernel<<<Nn, 256, 0, stream>>>(bufA, dinv, elist, off, b_gcn, bufB);

    // ---- pooling (two-stage) + head ----
    bounds_kernel<<<1, 128, 0, stream>>>(batch, starts);
    {
        dim3 pg(Gg, PSL);
        pool1_kernel<<<pg, 256, 0, stream>>>(bufB, fw, starts, pw, pmean, pmax);
    }
    pool2_kernel<<<Gg, 256, 0, stream>>>(pw, pmean, pmax, gfeat);
    head_kernel<<<Gg, 128, 0, stream>>>(gfeat, W_fc, b_fc, W_out, b_out, out);
}

// Round 7
// 805.044 us; speedup vs baseline: 1.2242x; 1.2242x over previous
//
#include <hip/hip_runtime.h>
#include <hip/hip_bf16.h>

// Problem constants (fixed by reference)
#define Nn     20000
#define Ee     240000
#define Gg     64
#define Ff     768
#define H1c    128
#define PEc    32
#define Dd     160      // H1 + PE
#define HEADSc 5
#define HCc    800      // HEADS * D
#define H2c    128
#define OUTc   16
#define ETot   (Ee + Nn)  // edges + self loops = 260000
#define NEG_SLOPE_F 0.2f

typedef short bf16x8 __attribute__((ext_vector_type(8)));
typedef float f32x4 __attribute__((ext_vector_type(4)));
typedef unsigned int u32;

// ---- bf16 split helpers (round-to-nearest-even) ----
__device__ __forceinline__ unsigned short bf_hi_rn(float v) {
    unsigned int u = __float_as_uint(v);
    return (unsigned short)((u + 0x7FFFu + ((u >> 16) & 1u)) >> 16);
}
__device__ __forceinline__ void bsplit(float v, unsigned short& h, unsigned short& l) {
    unsigned short hh = bf_hi_rn(v);
    float hf = __uint_as_float(((unsigned int)hh) << 16);
    l = bf_hi_rn(v - hf);
    h = hh;
}

// async global->LDS, 16 B per lane; LDS dest = wave-uniform base + lane*16
__device__ __forceinline__ void gl_lds16(const unsigned short* g, unsigned short* l) {
    __builtin_amdgcn_global_load_lds(
        (const __attribute__((address_space(1))) u32*)g,
        (__attribute__((address_space(3))) u32*)l, 16, 0, 0);
}

// ---------------------------------------------------------------------------
// Split fp32 array -> bf16 hi/lo arrays (same layout), vectorized by 4
// ---------------------------------------------------------------------------
__global__ void asplit_kernel(const float* __restrict__ A, unsigned short* __restrict__ Ah,
                              unsigned short* __restrict__ Al, int total4) {
    int i = blockIdx.x * 256 + threadIdx.x;
    if (i < total4) {
        float4 v = ((const float4*)A)[i];
        ushort4 h4, l4;
        bsplit(v.x, h4.x, l4.x);
        bsplit(v.y, h4.y, l4.y);
        bsplit(v.z, h4.z, l4.z);
        bsplit(v.w, h4.w, l4.w);
        ((ushort4*)Ah)[i] = h4;
        ((ushort4*)Al)[i] = l4;
    }
}

// Weight transpose + split: W[K][N] fp32 -> Wh/Wl[N][K] bf16
__global__ void wsplit_kernel(const float* __restrict__ W, unsigned short* __restrict__ Wh,
                              unsigned short* __restrict__ Wl, int K, int N) {
    int i = blockIdx.x * 256 + threadIdx.x;
    if (i < K * N) {
        int k = i / N, n = i % N;
        unsigned short h, l;
        bsplit(W[i], h, l);
        Wh[(size_t)n * K + k] = h;
        Wl[(size_t)n * K + k] = l;
    }
}

// ---------------------------------------------------------------------------
// bf16x3 MFMA GEMM, templated tile (BMxBN in {128x128, 64x64}).
// ---------------------------------------------------------------------------
#define KCHUNK 32

template<int ROWS>
__device__ __forceinline__ void stage_tile(const unsigned short* __restrict__ gsrc, int ld,
                                           int row0, int maxRow, int k0,
                                           unsigned short* lbuf, int wave, int lane) {
    #pragma unroll
    for (int p = 0; p < ROWS / 64; ++p) {
        int rb = wave * 16 + p * 64;
        int r = rb + (lane >> 2);
        int gr = min(row0 + r, maxRow);
        const unsigned short* g = gsrc + (size_t)gr * ld + k0 + (lane & 3) * 8;
        gl_lds16(g, lbuf + rb * 32);
    }
}

template<int BM, int BN, int OUT_MODE>
__global__ __launch_bounds__(256)
void gemm3_kernel(const unsigned short* __restrict__ Ah, const unsigned short* __restrict__ Al,
                  const unsigned short* __restrict__ Bh, const unsigned short* __restrict__ Bl,
                  const float* __restrict__ bias, float* __restrict__ C,
                  unsigned short* __restrict__ Ch, unsigned short* __restrict__ Cl,
                  int M, int N, int K, int lda, int ldc, int relu) {
    constexpr int TM = BM / 32;
    constexpr int TN = BN / 32;
    __shared__ __attribute__((aligned(16))) unsigned short As_h[BM * 32];
    __shared__ __attribute__((aligned(16))) unsigned short As_l[BM * 32];
    __shared__ __attribute__((aligned(16))) unsigned short Bs_h[BN * 32];
    __shared__ __attribute__((aligned(16))) unsigned short Bs_l[BN * 32];

    int tid = threadIdx.x;
    int m0 = blockIdx.x * BM, n0 = blockIdx.y * BN;
    int wave = tid >> 6, lane = tid & 63;
    int wm = (wave >> 1) * (16 * TM);
    int wn = (wave & 1) * (16 * TN);
    int fr = lane & 15;
    int fq = (lane >> 4) * 8;

    f32x4 acc[TM][TN] = {};

    for (int k0 = 0; k0 < K; k0 += KCHUNK) {
        stage_tile<BM>(Ah, lda, m0, M - 1, k0, As_h, wave, lane);
        stage_tile<BM>(Al, lda, m0, M - 1, k0, As_l, wave, lane);
        stage_tile<BN>(Bh, K,   n0, N - 1, k0, Bs_h, wave, lane);
        stage_tile<BN>(Bl, K,   n0, N - 1, k0, Bs_l, wave, lane);
        __syncthreads();

        bf16x8 a_h[TM], a_l[TM], b_h[TN], b_l[TN];
        #pragma unroll
        for (int i = 0; i < TM; ++i) {
            a_h[i] = *(const bf16x8*)&As_h[(wm + i * 16 + fr) * 32 + fq];
            a_l[i] = *(const bf16x8*)&As_l[(wm + i * 16 + fr) * 32 + fq];
        }
        #pragma unroll
        for (int j = 0; j < TN; ++j) {
            b_h[j] = *(const bf16x8*)&Bs_h[(wn + j * 16 + fr) * 32 + fq];
            b_l[j] = *(const bf16x8*)&Bs_l[(wn + j * 16 + fr) * 32 + fq];
        }
        #pragma unroll
        for (int j = 0; j < TN; ++j) {
            #pragma unroll
            for (int i = 0; i < TM; ++i) {
                acc[i][j] = __builtin_amdgcn_mfma_f32_16x16x32_bf16(a_h[i], b_h[j], acc[i][j], 0, 0, 0);
                acc[i][j] = __builtin_amdgcn_mfma_f32_16x16x32_bf16(a_h[i], b_l[j], acc[i][j], 0, 0, 0);
                acc[i][j] = __builtin_amdgcn_mfma_f32_16x16x32_bf16(a_l[i], b_h[j], acc[i][j], 0, 0, 0);
            }
        }
        __syncthreads();
    }

    int cr = (lane >> 4) * 4, cc = lane & 15;
    #pragma unroll
    for (int i = 0; i < TM; ++i) {
        #pragma unroll
        for (int j = 0; j < TN; ++j) {
            int c = n0 + wn + j * 16 + cc;
            if (c >= N) continue;
            float bv = bias ? bias[c] : 0.f;
            #pragma unroll
            for (int reg = 0; reg < 4; ++reg) {
                int r = m0 + wm + i * 16 + cr + reg;
                if (r >= M) continue;
                float v = acc[i][j][reg] + bv;
                if (relu) v = fmaxf(v, 0.f);
                if (OUT_MODE == 0) {
                    C[(size_t)r * ldc + c] = v;
                } else {
                    unsigned short hh, ll;
                    bsplit(v, hh, ll);
                    Ch[(size_t)r * ldc + c] = hh;
                    Cl[(size_t)r * ldc + c] = ll;
                }
            }
        }
    }
}

// copy pe_enc into h splits cols [128:160)
__global__ void pe_copy_kernel(const float* __restrict__ pe, unsigned short* __restrict__ hh,
                               unsigned short* __restrict__ hl) {
    int i = blockIdx.x * 256 + threadIdx.x;
    if (i < Nn * PEc) {
        int n = i / PEc, j = i % PEc;
        unsigned short h, l;
        bsplit(pe[i], h, l);
        hh[(size_t)n * Dd + H1c + j] = h;
        hl[(size_t)n * Dd + H1c + j] = l;
    }
}

// count in-degree (real edges only)
__global__ void count_kernel(const int* __restrict__ eidx, int* __restrict__ cnt) {
    int e = blockIdx.x * 256 + threadIdx.x;
    if (e < Ee) atomicAdd(&cnt[eidx[Ee + e]], 1);
}

// ---- multi-block exclusive scan over (cnt[i]+1) ----
#define NBLK 79  // ceil(20000/256)
__global__ void scan1_kernel(const int* __restrict__ cnt, int* __restrict__ off,
                             int* __restrict__ bsum) {
    __shared__ int sh[256];
    int t = threadIdx.x, i = blockIdx.x * 256 + t;
    int v = (i < Nn) ? (cnt[i] + 1) : 0;
    sh[t] = v;
    __syncthreads();
    for (int ofs = 1; ofs < 256; ofs <<= 1) {
        int add = (t >= ofs) ? sh[t - ofs] : 0;
        __syncthreads();
        sh[t] += add;
        __syncthreads();
    }
    if (i < Nn) off[i] = sh[t] - v;
    if (t == 255) bsum[blockIdx.x] = sh[255];
}
__global__ void scan2_kernel(int* __restrict__ bsum) {
    if (threadIdx.x == 0) {
        int acc = 0;
        for (int b = 0; b < NBLK; ++b) { int v = bsum[b]; bsum[b] = acc; acc += v; }
    }
}
__global__ void scan3_kernel(const int* __restrict__ cnt, int* __restrict__ off,
                             int* __restrict__ nxt, float* __restrict__ dinv,
                             const int* __restrict__ bsum) {
    int i = blockIdx.x * 256 + threadIdx.x;
    if (i < Nn) {
        int o = off[i] + bsum[blockIdx.x];
        off[i] = o;
        nxt[i] = o;
        dinv[i] = rsqrtf((float)(cnt[i] + 1));
    }
    if (i == 0) off[Nn] = ETot;
}

// scatter edges (and self loops) into CSR by dst
__global__ void scatter_kernel(const int* __restrict__ eidx, int* __restrict__ nxt,
                               int* __restrict__ elist, int* __restrict__ edst) {
    int e = blockIdx.x * 256 + threadIdx.x;
    if (e < ETot) {
        int s, d;
        if (e < Ee) { s = eidx[e]; d = eidx[Ee + e]; }
        else        { s = e - Ee; d = s; }
        int slot = atomicAdd(&nxt[d], 1);
        elist[slot] = s;
        edst[slot] = d;
    }
}

// ---------------------------------------------------------------------------
// FUSED GATv2, single-read register version. Per 8-edge chunk:
//   1) 200 threads load their float4 of all 8 src rows into REGISTERS,
//      compute 8 score partials -> LDS
//   2) 40 threads reduce one (edge,head) each; 5 threads do the chunk
//      online-softmax update (same wave, LDS-ordered, no extra barrier)
//   3) all threads aggregate their register-held vl with the 8 weights
// 3 barriers / 8 edges; x_l read exactly once per edge.
// ---------------------------------------------------------------------------
#define FCH 8
__global__ __launch_bounds__(256)
void fused_gat_kernel(const float* __restrict__ xl, const float* __restrict__ xr,
                      const float* __restrict__ att, const int* __restrict__ elist,
                      const int* __restrict__ off, const float* __restrict__ gat_bias,
                      unsigned short* __restrict__ g1h, unsigned short* __restrict__ g1l) {
    int d = blockIdx.x;
    int t = threadIdx.x;
    __shared__ float sh_red[FCH][200];
    __shared__ float sh_sc[FCH][HEADSc];
    __shared__ float sh_w[FCH][HEADSc];
    __shared__ float sh_scale[HEADSc], sh_m[HEADSc], sh_den[HEADSc];
    __shared__ int sh_src[FCH];
    int e0 = off[d], e1 = off[d + 1];
    int cnt = e1 - e0;
    bool act = t < 200;
    int hd = act ? (t / 40) : 0;
    float4 vr = {0.f, 0.f, 0.f, 0.f}, va = {0.f, 0.f, 0.f, 0.f};
    if (act) {
        vr = ((const float4*)(xr + (size_t)d * HCc))[t];
        va = ((const float4*)att)[t];
    }
    if (t < HEADSc) { sh_m[t] = -1e30f; sh_den[t] = 0.f; }
    float4 acc = {0.f, 0.f, 0.f, 0.f};

    for (int base = 0; base < cnt; base += FCH) {
        int nc = min(FCH, cnt - base);
        if (t < FCH) sh_src[t] = elist[e0 + base + min(t, nc - 1)];
        __syncthreads();   // src visible (also fences prev chunk's sh_w reads)
        float4 vl[FCH];
        if (act) {
            #pragma unroll
            for (int e = 0; e < FCH; ++e)
                vl[e] = ((const float4*)(xl + (size_t)sh_src[e] * HCc))[t];
            #pragma unroll
            for (int e = 0; e < FCH; ++e) {
                float p = 0.f, m, lm;
                m = vl[e].x + vr.x; lm = fmaxf(m, 0.2f * m); p = fmaf(lm, va.x, p);
                m = vl[e].y + vr.y; lm = fmaxf(m, 0.2f * m); p = fmaf(lm, va.y, p);
                m = vl[e].z + vr.z; lm = fmaxf(m, 0.2f * m); p = fmaf(lm, va.z, p);
                m = vl[e].w + vr.w; lm = fmaxf(m, 0.2f * m); p = fmaf(lm, va.w, p);
                sh_red[e][t] = p;
            }
        }
        __syncthreads();   // partials visible
        if (t < 40) {      // one (edge,head) per thread — all in wave 0
            int e = t & 7, h = t >> 3;
            float s = 0.f;
            const float* pr = &sh_red[e][h * 40];
            #pragma unroll
            for (int k = 0; k < 40; ++k) s += pr[k];
            sh_sc[e][h] = (e < nc) ? s : -1e30f;
        }
        if (t < HEADSc) {  // same wave as stage above: LDS ops stay ordered
            float mo = sh_m[t];
            float mn = mo;
            #pragma unroll
            for (int e = 0; e < FCH; ++e) mn = fmaxf(mn, sh_sc[e][t]);
            float sc = __expf(mo - mn);
            float den = sh_den[t] * sc;
            #pragma unroll
            for (int e = 0; e < FCH; ++e) {
                float w = __expf(sh_sc[e][t] - mn);
                sh_w[e][t] = w;
                den += w;
            }
            sh_den[t] = den;
            sh_m[t] = mn;
            sh_scale[t] = sc;
        }
        __syncthreads();   // weights visible
        if (act) {
            float sc = sh_scale[hd];
            acc.x *= sc; acc.y *= sc; acc.z *= sc; acc.w *= sc;
            #pragma unroll
            for (int e = 0; e < FCH; ++e) {
                float w = sh_w[e][hd];   // 0 for invalid tail edges
                acc.x = fmaf(w, vl[e].x, acc.x);
                acc.y = fmaf(w, vl[e].y, acc.y);
                acc.z = fmaf(w, vl[e].z, acc.z);
                acc.w = fmaf(w, vl[e].w, acc.w);
            }
        }
    }
    if (act) {
        float inv = 1.f / sh_den[hd];
        float4 bv = ((const float4*)gat_bias)[t];
        ushort4 oh, ol;
        float v;
        v = fmaxf(fmaf(acc.x, inv, bv.x), 0.f); bsplit(v, oh.x, ol.x);
        v = fmaxf(fmaf(acc.y, inv, bv.y), 0.f); bsplit(v, oh.y, ol.y);
        v = fmaxf(fmaf(acc.z, inv, bv.z), 0.f); bsplit(v, oh.z, ol.z);
        v = fmaxf(fmaf(acc.w, inv, bv.w), 0.f); bsplit(v, oh.w, ol.w);
        *(ushort4*)(g1h + (size_t)d * HCc + 4 * t) = oh;
        *(ushort4*)(g1l + (size_t)d * HCc + 4 * t) = ol;
    }
}

// GCN aggregate, float4 form: g2[d] = relu(dinv[d] * sum dinv[src]*hg[src] + b)
__global__ __launch_bounds__(256)
void gcn_kernel(const float* __restrict__ hg, const float* __restrict__ dinv,
                const int* __restrict__ elist, const int* __restrict__ off,
                const float* __restrict__ b_gcn, float* __restrict__ g2) {
    int d = blockIdx.x;
    int t = threadIdx.x;
    __shared__ int src_s[64];
    __shared__ float w_s[64];
    int e0 = off[d], e1 = off[d + 1];
    int cnt = e1 - e0;
    float di = dinv[d];
    float4 acc = {0.f, 0.f, 0.f, 0.f};
    for (int base = 0; base < cnt; base += 64) {
        int nc = min(64, cnt - base);
        if (t < nc) {
            int s = elist[e0 + base + t];
            src_s[t] = s;
            w_s[t] = dinv[s];
        }
        __syncthreads();
        if (t < 200) {
            for (int el = 0; el < nc; ++el) {
                const float4* p = (const float4*)(hg + (size_t)src_s[el] * HCc);
                float w = w_s[el];
                float4 v = p[t];
                acc.x = fmaf(w, v.x, acc.x);
                acc.y = fmaf(w, v.y, acc.y);
                acc.z = fmaf(w, v.z, acc.z);
                acc.w = fmaf(w, v.w, acc.w);
            }
        }
        __syncthreads();
    }
    if (t < 200) {
        float4 bv = ((const float4*)b_gcn)[t];
        float4 o;
        o.x = fmaxf(acc.x * di + bv.x, 0.f);
        o.y = fmaxf(acc.y * di + bv.y, 0.f);
        o.z = fmaxf(acc.z * di + bv.z, 0.f);
        o.w = fmaxf(acc.w * di + bv.w, 0.f);
        *(float4*)(g2 + (size_t)d * HCc + 4 * t) = o;
    }
}

// graph boundaries in sorted batch (lower bound per graph)
__global__ void bounds_kernel(const int* __restrict__ batch, int* __restrict__ starts) {
    int g = threadIdx.x;
    if (g <= Gg) {
        if (g == Gg) { starts[Gg] = Nn; return; }
        int lo = 0, hi = Nn;
        while (lo < hi) {
            int mid = (lo + hi) >> 1;
            if (batch[mid] < g) lo = mid + 1; else hi = mid;
        }
        starts[g] = lo;
    }
}

// ---- two-stage pool: node-sliced partials, then combine ----
#define PSL 4
__global__ __launch_bounds__(256)
void pool1_kernel(const float* __restrict__ g2, const float* __restrict__ fw,
                  const int* __restrict__ starts, float* __restrict__ pw,
                  float* __restrict__ pmean, float* __restrict__ pmax) {
    int g = blockIdx.x, s = blockIdx.y, t = threadIdx.x;
    int n0 = starts[g], n1 = starts[g + 1];
    int len = n1 - n0;
    int q0 = n0 + (int)(((long long)len * s) / PSL);
    int q1 = n0 + (int)(((long long)len * (s + 1)) / PSL);
    __shared__ float red[256];
    float wsum = 0.f;
    for (int n = q0 + t; n < q1; n += 256) wsum += fw[n];
    red[t] = wsum;
    __syncthreads();
    for (int ofs = 128; ofs > 0; ofs >>= 1) {
        if (t < ofs) red[t] += red[t + ofs];
        __syncthreads();
    }
    if (t == 0) pw[g * PSL + s] = red[0];
    if (t < 200) {
        float4 sum = {0.f, 0.f, 0.f, 0.f};
        float4 mx = {0.f, 0.f, 0.f, 0.f};
        for (int n = q0; n < q1; ++n) {
            float w = fw[n];
            float4 v = ((const float4*)(g2 + (size_t)n * HCc))[t];
            sum.x = fmaf(w, v.x, sum.x); sum.y = fmaf(w, v.y, sum.y);
            sum.z = fmaf(w, v.z, sum.z); sum.w = fmaf(w, v.w, sum.w);
            mx.x = fmaxf(mx.x, v.x); mx.y = fmaxf(mx.y, v.y);
            mx.z = fmaxf(mx.z, v.z); mx.w = fmaxf(mx.w, v.w);
        }
        size_t o = ((size_t)g * PSL + s) * HCc + 4 * t;
        *(float4*)(pmean + o) = sum;
        *(float4*)(pmax + o) = mx;
    }
}
__global__ __launch_bounds__(256)
void pool2_kernel(const float* __restrict__ pw, const float* __restrict__ pmean,
                  const float* __restrict__ pmax, float* __restrict__ gfeat) {
    int g = blockIdx.x, t = threadIdx.x;
    if (t >= 200) return;
    float wsg = 0.f;
    #pragma unroll
    for (int s = 0; s < PSL; ++s) wsg += pw[g * PSL + s];
    wsg = fmaxf(wsg, 1e-6f);
    float inv = 1.f / wsg;
    float4 sum = {0.f, 0.f, 0.f, 0.f};
    float4 mx = {0.f, 0.f, 0.f, 0.f};
    #pragma unroll
    for (int s = 0; s < PSL; ++s) {
        size_t o = ((size_t)g * PSL + s) * HCc + 4 * t;
        float4 a = *(const float4*)(pmean + o);
        float4 b = *(const float4*)(pmax + o);
        sum.x += a.x; sum.y += a.y; sum.z += a.z; sum.w += a.w;
        mx.x = fmaxf(mx.x, b.x); mx.y = fmaxf(mx.y, b.y);
        mx.z = fmaxf(mx.z, b.z); mx.w = fmaxf(mx.w, b.w);
    }
    float* gm = gfeat + (size_t)g * (2 * HCc);
    sum.x *= inv; sum.y *= inv; sum.z *= inv; sum.w *= inv;
    *(float4*)(gm + 4 * t) = sum;
    *(float4*)(gm + HCc + 4 * t) = mx;
}

// final MLP head: out = relu(relu(gfeat@W_fc + b_fc) @ W_out + b_out)
__global__ __launch_bounds__(128)
void head_kernel(const float* __restrict__ gfeat, const float* __restrict__ W_fc,
                 const float* __restrict__ b_fc, const float* __restrict__ W_out,
                 const float* __restrict__ b_out, float* __restrict__ out) {
    int g = blockIdx.x;
    int t = threadIdx.x;  // 128
    __shared__ float gf[2 * HCc];
    __shared__ float fc1[H2c];
    for (int i = t; i < 2 * HCc; i += 128) gf[i] = gfeat[(size_t)g * (2 * HCc) + i];
    __syncthreads();
    float a0 = 0.f, a1 = 0.f, a2 = 0.f, a3 = 0.f;
    for (int k = 0; k < 2 * HCc; k += 4) {
        a0 = fmaf(gf[k],     W_fc[(size_t)k * H2c + t], a0);
        a1 = fmaf(gf[k + 1], W_fc[(size_t)(k + 1) * H2c + t], a1);
        a2 = fmaf(gf[k + 2], W_fc[(size_t)(k + 2) * H2c + t], a2);
        a3 = fmaf(gf[k + 3], W_fc[(size_t)(k + 3) * H2c + t], a3);
    }
    fc1[t] = fmaxf(b_fc[t] + ((a0 + a1) + (a2 + a3)), 0.f);
    __syncthreads();
    if (t < OUTc) {
        float o = b_out[t];
        #pragma unroll 8
        for (int k = 0; k < H2c; ++k) o += fc1[k] * W_out[k * OUTc + t];
        out[g * OUTc + t] = fmaxf(o, 0.f);
    }
}

extern "C" void kernel_launch(void* const* d_in, const int* in_sizes, int n_in,
                              void* d_out, int out_size, void* d_ws, size_t ws_size,
                              hipStream_t stream) {
    (void)in_sizes; (void)n_in; (void)out_size; (void)ws_size;
    const float* x        = (const float*)d_in[0];
    const float* pe       = (const float*)d_in[1];
    const int*   eidx     = (const int*)d_in[2];
    const int*   batch    = (const int*)d_in[3];
    const float* fw       = (const float*)d_in[4];
    const float* W_pre    = (const float*)d_in[6];
    const float* b_pre    = (const float*)d_in[7];
    const float* W_l      = (const float*)d_in[8];
    const float* b_l      = (const float*)d_in[9];
    const float* W_r      = (const float*)d_in[10];
    const float* b_r      = (const float*)d_in[11];
    const float* att      = (const float*)d_in[12];
    const float* gat_bias = (const float*)d_in[13];
    const float* W_gcn    = (const float*)d_in[14];
    const float* b_gcn    = (const float*)d_in[15];
    const float* W_fc     = (const float*)d_in[16];
    const float* b_fc     = (const float*)d_in[17];
    const float* W_out    = (const float*)d_in[18];
    const float* b_out    = (const float*)d_in[19];
    float* out = (float*)d_out;

    // ---- workspace carving ----
    char* p = (char*)d_ws;
    auto alloc = [&](size_t bytes) {
        char* r = p;
        p += (bytes + 255) & ~(size_t)255;
        return r;
    };
    unsigned short* hh = (unsigned short*)alloc((size_t)Nn * Dd * 2 * 2);
    unsigned short* hl = hh + (size_t)Nn * Dd;
    float* bufA = (float*)alloc((size_t)Nn * HCc * 4);  // xl, later hg
    float* bufB = (float*)alloc((size_t)Nn * HCc * 4);  // xr, later g2
    float* bufC = (float*)alloc((size_t)Nn * HCc * 4);  // x splits, later g1 splits
    int*   cnt    = (int*)alloc((size_t)Nn * 4);
    int*   off    = (int*)alloc((size_t)(Nn + 1) * 4);
    int*   nxt    = (int*)alloc((size_t)Nn * 4);
    float* dinv   = (float*)alloc((size_t)Nn * 4);
    int*   elist  = (int*)alloc((size_t)ETot * 4);
    int*   edst   = (int*)alloc((size_t)ETot * 4);
    int*   starts = (int*)alloc((size_t)(Gg + 1) * 4);
    float* gfeat  = (float*)alloc((size_t)Gg * 2 * HCc * 4);
    int*   bsum   = (int*)alloc((size_t)NBLK * 4);
    float* pw     = (float*)alloc((size_t)Gg * PSL * 4);
    float* pmean  = (float*)alloc((size_t)Gg * PSL * HCc * 4);
    float* pmax   = (float*)alloc((size_t)Gg * PSL * HCc * 4);
    unsigned short* WpreTh = (unsigned short*)alloc((size_t)Ff * H1c * 2 * 2);
    unsigned short* WpreTl = WpreTh + (size_t)Ff * H1c;
    unsigned short* WlTh   = (unsigned short*)alloc((size_t)Dd * HCc * 2 * 2);
    unsigned short* WlTl   = WlTh + (size_t)Dd * HCc;
    unsigned short* WrTh   = (unsigned short*)alloc((size_t)Dd * HCc * 2 * 2);
    unsigned short* WrTl   = WrTh + (size_t)Dd * HCc;
    unsigned short* WgTh   = (unsigned short*)alloc((size_t)HCc * HCc * 2 * 2);
    unsigned short* WgTl   = WgTh + (size_t)HCc * HCc;

    // aliases (disjoint lifetimes within bufC)
    unsigned short* xh  = (unsigned short*)bufC;   // x splits: prep -> GEMM1
    unsigned short* xlo = xh + (size_t)Nn * Ff;
    unsigned short* g1h = (unsigned short*)bufC;   // g1 splits: fused agg -> GEMM4
    unsigned short* g1l = g1h + (size_t)Nn * HCc;

    // ---- CSR build ----
    hipMemsetAsync(cnt, 0, (size_t)Nn * 4, stream);
    count_kernel<<<(Ee + 255) / 256, 256, 0, stream>>>(eidx, cnt);
    scan1_kernel<<<NBLK, 256, 0, stream>>>(cnt, off, bsum);
    scan2_kernel<<<1, 64, 0, stream>>>(bsum);
    scan3_kernel<<<NBLK, 256, 0, stream>>>(cnt, off, nxt, dinv, bsum);
    scatter_kernel<<<(ETot + 255) / 256, 256, 0, stream>>>(eidx, nxt, elist, edst);

    // ---- splits ----
    asplit_kernel<<<(Nn * Ff / 4 + 255) / 256, 256, 0, stream>>>(x, xh, xlo, Nn * Ff / 4);
    wsplit_kernel<<<(Ff * H1c + 255) / 256, 256, 0, stream>>>(W_pre, WpreTh, WpreTl, Ff, H1c);
    wsplit_kernel<<<(Dd * HCc + 255) / 256, 256, 0, stream>>>(W_l, WlTh, WlTl, Dd, HCc);
    wsplit_kernel<<<(Dd * HCc + 255) / 256, 256, 0, stream>>>(W_r, WrTh, WrTl, Dd, HCc);
    wsplit_kernel<<<(HCc * HCc + 255) / 256, 256, 0, stream>>>(W_gcn, WgTh, WgTl, HCc, HCc);

    // ---- GEMM1 (64x64 tile): h = relu(x@W_pre+b) -> h splits ----
    {
        dim3 grid((Nn + 63) / 64, (H1c + 63) / 64);
        gemm3_kernel<64, 64, 1><<<grid, 256, 0, stream>>>(
            xh, xlo, WpreTh, WpreTl, b_pre, nullptr, hh, hl,
            Nn, H1c, Ff, Ff, Dd, 1);
    }
    pe_copy_kernel<<<(Nn * PEc + 255) / 256, 256, 0, stream>>>(pe, hh, hl);

    // ---- GEMM2/3: xl = h@W_l + b_l -> bufA ; xr = h@W_r + b_r -> bufB ----
    {
        dim3 grid((Nn + 127) / 128, (HCc + 127) / 128);
        gemm3_kernel<128, 128, 0><<<grid, 256, 0, stream>>>(
            hh, hl, WlTh, WlTl, b_l, bufA, nullptr, nullptr,
            Nn, HCc, Dd, Dd, HCc, 0);
        gemm3_kernel<128, 128, 0><<<grid, 256, 0, stream>>>(
            hh, hl, WrTh, WrTl, b_r, bufB, nullptr, nullptr,
            Nn, HCc, Dd, Dd, HCc, 0);
    }

    // ---- FUSED GATv2 (single-read, 8-edge chunks) -> g1 (bufC) ----
    fused_gat_kernel<<<Nn, 256, 0, stream>>>(bufA, bufB, att, elist, off,
                                             gat_bias, g1h, g1l);

    // ---- GEMM4: hg = g1 @ W_gcn -> bufA (xl dead) ----
    {
        dim3 grid((Nn + 127) / 128, (HCc + 127) / 128);
        gemm3_kernel<128, 128, 0><<<grid, 256, 0, stream>>>(
            g1h, g1l, WgTh, WgTl, nullptr, bufA, nullptr, nullptr,
            Nn, HCc, HCc, HCc, HCc, 0);
    }
    // ---- GCN aggregate -> g2 (bufB, xr dead) ----
    gcn_kernel<<<Nn, 256, 0, stream>>>(bufA, dinv, elist, off, b_gcn, bufB);

    // ---- pooling (two-stage) + head ----
    bounds_kernel<<<1, 128, 0, stream>>>(batch, starts);
    {
        dim3 pg(Gg, PSL);
        pool1_kernel<<<pg, 256, 0, stream>>>(bufB, fw, starts, pw, pmean, pmax);
    }
    pool2_kernel<<<Gg, 256, 0, stream>>>(pw, pmean, pmax, gfeat);
    head_kernel<<<Gg, 128, 0, stream>>>(gfeat, W_fc, b_fc, W_out, b_out, out);
}

// Round 8
// 795.379 us; speedup vs baseline: 1.2391x; 1.0122x over previous
//
#include <hip/hip_runtime.h>
#include <hip/hip_bf16.h>

// Problem constants (fixed by reference)
#define Nn     20000
#define Ee     240000
#define Gg     64
#define Ff     768
#define H1c    128
#define PEc    32
#define Dd     160      // H1 + PE
#define HEADSc 5
#define HCc    800      // HEADS * D
#define H2c    128
#define OUTc   16
#define ETot   (Ee + Nn)  // edges + self loops = 260000
#define NEG_SLOPE_F 0.2f

typedef short bf16x8 __attribute__((ext_vector_type(8)));
typedef float f32x4 __attribute__((ext_vector_type(4)));
typedef unsigned int u32;

// ---- bf16 split helpers (round-to-nearest-even) ----
__device__ __forceinline__ unsigned short bf_hi_rn(float v) {
    unsigned int u = __float_as_uint(v);
    return (unsigned short)((u + 0x7FFFu + ((u >> 16) & 1u)) >> 16);
}
__device__ __forceinline__ void bsplit(float v, unsigned short& h, unsigned short& l) {
    unsigned short hh = bf_hi_rn(v);
    float hf = __uint_as_float(((unsigned int)hh) << 16);
    l = bf_hi_rn(v - hf);
    h = hh;
}

// async global->LDS, 16 B per lane; LDS dest = wave-uniform base + lane*16
__device__ __forceinline__ void gl_lds16(const unsigned short* g, unsigned short* l) {
    __builtin_amdgcn_global_load_lds(
        (const __attribute__((address_space(1))) u32*)g,
        (__attribute__((address_space(3))) u32*)l, 16, 0, 0);
}

// ---------------------------------------------------------------------------
// Split fp32 array -> bf16 hi/lo arrays (same layout), vectorized by 4
// ---------------------------------------------------------------------------
__global__ void asplit_kernel(const float* __restrict__ A, unsigned short* __restrict__ Ah,
                              unsigned short* __restrict__ Al, int total4) {
    int i = blockIdx.x * 256 + threadIdx.x;
    if (i < total4) {
        float4 v = ((const float4*)A)[i];
        ushort4 h4, l4;
        bsplit(v.x, h4.x, l4.x);
        bsplit(v.y, h4.y, l4.y);
        bsplit(v.z, h4.z, l4.z);
        bsplit(v.w, h4.w, l4.w);
        ((ushort4*)Ah)[i] = h4;
        ((ushort4*)Al)[i] = l4;
    }
}

// Weight transpose + split: W[K][N] fp32 -> Wh/Wl[N][K] bf16
__global__ void wsplit_kernel(const float* __restrict__ W, unsigned short* __restrict__ Wh,
                              unsigned short* __restrict__ Wl, int K, int N) {
    int i = blockIdx.x * 256 + threadIdx.x;
    if (i < K * N) {
        int k = i / N, n = i % N;
        unsigned short h, l;
        bsplit(W[i], h, l);
        Wh[(size_t)n * K + k] = h;
        Wl[(size_t)n * K + k] = l;
    }
}

// ---------------------------------------------------------------------------
// bf16x3 MFMA GEMM, templated tile.
// OUT_MODE 0: fp32 C; 1: bf16 hi/lo split out; 2: dual fp32 dest split at col 800.
// ---------------------------------------------------------------------------
#define KCHUNK 32

template<int ROWS>
__device__ __forceinline__ void stage_tile(const unsigned short* __restrict__ gsrc, int ld,
                                           int row0, int maxRow, int k0,
                                           unsigned short* lbuf, int wave, int lane) {
    #pragma unroll
    for (int p = 0; p < ROWS / 64; ++p) {
        int rb = wave * 16 + p * 64;
        int r = rb + (lane >> 2);
        int gr = min(row0 + r, maxRow);
        const unsigned short* g = gsrc + (size_t)gr * ld + k0 + (lane & 3) * 8;
        gl_lds16(g, lbuf + rb * 32);
    }
}

template<int BM, int BN, int OUT_MODE>
__global__ __launch_bounds__(256)
void gemm3_kernel(const unsigned short* __restrict__ Ah, const unsigned short* __restrict__ Al,
                  const unsigned short* __restrict__ Bh, const unsigned short* __restrict__ Bl,
                  const float* __restrict__ bias, const float* __restrict__ bias2,
                  float* __restrict__ C, float* __restrict__ C2,
                  unsigned short* __restrict__ Ch, unsigned short* __restrict__ Cl,
                  int M, int N, int K, int lda, int ldc, int relu) {
    constexpr int TM = BM / 32;
    constexpr int TN = BN / 32;
    __shared__ __attribute__((aligned(16))) unsigned short As_h[BM * 32];
    __shared__ __attribute__((aligned(16))) unsigned short As_l[BM * 32];
    __shared__ __attribute__((aligned(16))) unsigned short Bs_h[BN * 32];
    __shared__ __attribute__((aligned(16))) unsigned short Bs_l[BN * 32];

    int tid = threadIdx.x;
    int m0 = blockIdx.x * BM, n0 = blockIdx.y * BN;
    int wave = tid >> 6, lane = tid & 63;
    int wm = (wave >> 1) * (16 * TM);
    int wn = (wave & 1) * (16 * TN);
    int fr = lane & 15;
    int fq = (lane >> 4) * 8;

    f32x4 acc[TM][TN] = {};

    for (int k0 = 0; k0 < K; k0 += KCHUNK) {
        stage_tile<BM>(Ah, lda, m0, M - 1, k0, As_h, wave, lane);
        stage_tile<BM>(Al, lda, m0, M - 1, k0, As_l, wave, lane);
        stage_tile<BN>(Bh, K,   n0, N - 1, k0, Bs_h, wave, lane);
        stage_tile<BN>(Bl, K,   n0, N - 1, k0, Bs_l, wave, lane);
        __syncthreads();

        bf16x8 a_h[TM], a_l[TM], b_h[TN], b_l[TN];
        #pragma unroll
        for (int i = 0; i < TM; ++i) {
            a_h[i] = *(const bf16x8*)&As_h[(wm + i * 16 + fr) * 32 + fq];
            a_l[i] = *(const bf16x8*)&As_l[(wm + i * 16 + fr) * 32 + fq];
        }
        #pragma unroll
        for (int j = 0; j < TN; ++j) {
            b_h[j] = *(const bf16x8*)&Bs_h[(wn + j * 16 + fr) * 32 + fq];
            b_l[j] = *(const bf16x8*)&Bs_l[(wn + j * 16 + fr) * 32 + fq];
        }
        #pragma unroll
        for (int j = 0; j < TN; ++j) {
            #pragma unroll
            for (int i = 0; i < TM; ++i) {
                acc[i][j] = __builtin_amdgcn_mfma_f32_16x16x32_bf16(a_h[i], b_h[j], acc[i][j], 0, 0, 0);
                acc[i][j] = __builtin_amdgcn_mfma_f32_16x16x32_bf16(a_h[i], b_l[j], acc[i][j], 0, 0, 0);
                acc[i][j] = __builtin_amdgcn_mfma_f32_16x16x32_bf16(a_l[i], b_h[j], acc[i][j], 0, 0, 0);
            }
        }
        __syncthreads();
    }

    int cr = (lane >> 4) * 4, cc = lane & 15;
    #pragma unroll
    for (int i = 0; i < TM; ++i) {
        #pragma unroll
        for (int j = 0; j < TN; ++j) {
            int c = n0 + wn + j * 16 + cc;
            if (c >= N) continue;
            float bv;
            if (OUT_MODE == 2) bv = (c < HCc) ? bias[c] : bias2[c - HCc];
            else bv = bias ? bias[c] : 0.f;
            #pragma unroll
            for (int reg = 0; reg < 4; ++reg) {
                int r = m0 + wm + i * 16 + cr + reg;
                if (r >= M) continue;
                float v = acc[i][j][reg] + bv;
                if (relu) v = fmaxf(v, 0.f);
                if (OUT_MODE == 0) {
                    C[(size_t)r * ldc + c] = v;
                } else if (OUT_MODE == 2) {
                    if (c < HCc) C[(size_t)r * HCc + c] = v;
                    else         C2[(size_t)r * HCc + (c - HCc)] = v;
                } else {
                    unsigned short hh, ll;
                    bsplit(v, hh, ll);
                    Ch[(size_t)r * ldc + c] = hh;
                    Cl[(size_t)r * ldc + c] = ll;
                }
            }
        }
    }
}

// copy pe_enc into h splits cols [128:160)
__global__ void pe_copy_kernel(const float* __restrict__ pe, unsigned short* __restrict__ hh,
                               unsigned short* __restrict__ hl) {
    int i = blockIdx.x * 256 + threadIdx.x;
    if (i < Nn * PEc) {
        int n = i / PEc, j = i % PEc;
        unsigned short h, l;
        bsplit(pe[i], h, l);
        hh[(size_t)n * Dd + H1c + j] = h;
        hl[(size_t)n * Dd + H1c + j] = l;
    }
}

// count in-degree (real edges only)
__global__ void count_kernel(const int* __restrict__ eidx, int* __restrict__ cnt) {
    int e = blockIdx.x * 256 + threadIdx.x;
    if (e < Ee) atomicAdd(&cnt[eidx[Ee + e]], 1);
}

// ---- multi-block exclusive scan over (cnt[i]+1) ----
#define NBLK 79  // ceil(20000/256)
__global__ void scan1_kernel(const int* __restrict__ cnt, int* __restrict__ off,
                             int* __restrict__ bsum) {
    __shared__ int sh[256];
    int t = threadIdx.x, i = blockIdx.x * 256 + t;
    int v = (i < Nn) ? (cnt[i] + 1) : 0;
    sh[t] = v;
    __syncthreads();
    for (int ofs = 1; ofs < 256; ofs <<= 1) {
        int add = (t >= ofs) ? sh[t - ofs] : 0;
        __syncthreads();
        sh[t] += add;
        __syncthreads();
    }
    if (i < Nn) off[i] = sh[t] - v;
    if (t == 255) bsum[blockIdx.x] = sh[255];
}
__global__ void scan2_kernel(int* __restrict__ bsum) {
    if (threadIdx.x == 0) {
        int acc = 0;
        for (int b = 0; b < NBLK; ++b) { int v = bsum[b]; bsum[b] = acc; acc += v; }
    }
}
__global__ void scan3_kernel(const int* __restrict__ cnt, int* __restrict__ off,
                             int* __restrict__ nxt, float* __restrict__ dinv,
                             const int* __restrict__ bsum) {
    int i = blockIdx.x * 256 + threadIdx.x;
    if (i < Nn) {
        int o = off[i] + bsum[blockIdx.x];
        off[i] = o;
        nxt[i] = o;
        dinv[i] = rsqrtf((float)(cnt[i] + 1));
    }
    if (i == 0) off[Nn] = ETot;
}

// scatter edges (and self loops) into CSR by dst
__global__ void scatter_kernel(const int* __restrict__ eidx, int* __restrict__ nxt,
                               int* __restrict__ elist) {
    int e = blockIdx.x * 256 + threadIdx.x;
    if (e < ETot) {
        int s, d;
        if (e < Ee) { s = eidx[e]; d = eidx[Ee + e]; }
        else        { s = e - Ee; d = s; }
        int slot = atomicAdd(&nxt[d], 1);
        elist[slot] = s;
    }
}

// ---------------------------------------------------------------------------
// FUSED GATv2, single-read register version. Per 16-edge chunk:
//   1) 200 threads load their float4 of all 16 src rows into REGISTERS,
//      compute 16 score partials -> LDS
//   2) 40 threads reduce two (edge,head) pairs each; 5 threads do the chunk
//      online-softmax update (all wave 0 -> LDS-ordered, no extra barrier)
//   3) all threads aggregate their register-held vl with the 16 weights
// 3 barriers per chunk; avg degree 13 -> most blocks run ONE chunk.
// ---------------------------------------------------------------------------
#define FCH 16
__global__ __launch_bounds__(256)
void fused_gat_kernel(const float* __restrict__ xl, const float* __restrict__ xr,
                      const float* __restrict__ att, const int* __restrict__ elist,
                      const int* __restrict__ off, const float* __restrict__ gat_bias,
                      unsigned short* __restrict__ g1h, unsigned short* __restrict__ g1l) {
    int d = blockIdx.x;
    int t = threadIdx.x;
    __shared__ float sh_red[FCH][200];
    __shared__ float sh_sc[FCH][HEADSc];
    __shared__ float sh_w[FCH][HEADSc];
    __shared__ float sh_scale[HEADSc], sh_m[HEADSc], sh_den[HEADSc];
    __shared__ int sh_src[FCH];
    int e0 = off[d], e1 = off[d + 1];
    int cnt = e1 - e0;
    bool act = t < 200;
    int hd = act ? (t / 40) : 0;
    float4 vr = {0.f, 0.f, 0.f, 0.f}, va = {0.f, 0.f, 0.f, 0.f};
    if (act) {
        vr = ((const float4*)(xr + (size_t)d * HCc))[t];
        va = ((const float4*)att)[t];
    }
    if (t < HEADSc) { sh_m[t] = -1e30f; sh_den[t] = 0.f; }
    float4 acc = {0.f, 0.f, 0.f, 0.f};

    for (int base = 0; base < cnt; base += FCH) {
        int nc = min(FCH, cnt - base);
        if (t < FCH) sh_src[t] = elist[e0 + base + min(t, nc - 1)];
        __syncthreads();   // src visible (also fences prev chunk's sh_w reads)
        float4 vl[FCH];
        if (act) {
            #pragma unroll
            for (int e = 0; e < FCH; ++e)
                vl[e] = ((const float4*)(xl + (size_t)sh_src[e] * HCc))[t];
            #pragma unroll
            for (int e = 0; e < FCH; ++e) {
                float p = 0.f, m, lm;
                m = vl[e].x + vr.x; lm = fmaxf(m, 0.2f * m); p = fmaf(lm, va.x, p);
                m = vl[e].y + vr.y; lm = fmaxf(m, 0.2f * m); p = fmaf(lm, va.y, p);
                m = vl[e].z + vr.z; lm = fmaxf(m, 0.2f * m); p = fmaf(lm, va.z, p);
                m = vl[e].w + vr.w; lm = fmaxf(m, 0.2f * m); p = fmaf(lm, va.w, p);
                sh_red[e][t] = p;
            }
        }
        __syncthreads();   // partials visible
        if (t < 40) {      // two (edge,head) pairs per thread — all wave 0
            int e = t & 7, h = t >> 3;
            float s0 = 0.f, s1 = 0.f;
            const float* p0 = &sh_red[e][h * 40];
            const float* p1 = &sh_red[e + 8][h * 40];
            #pragma unroll
            for (int k = 0; k < 40; ++k) { s0 += p0[k]; s1 += p1[k]; }
            sh_sc[e][h]     = (e < nc)     ? s0 : -1e30f;
            sh_sc[e + 8][h] = (e + 8 < nc) ? s1 : -1e30f;
        }
        if (t < HEADSc) {  // same wave: LDS ops stay ordered
            float mo = sh_m[t];
            float mn = mo;
            #pragma unroll
            for (int e = 0; e < FCH; ++e) mn = fmaxf(mn, sh_sc[e][t]);
            float sc = __expf(mo - mn);
            float den = sh_den[t] * sc;
            #pragma unroll
            for (int e = 0; e < FCH; ++e) {
                float w = __expf(sh_sc[e][t] - mn);
                sh_w[e][t] = w;
                den += w;
            }
            sh_den[t] = den;
            sh_m[t] = mn;
            sh_scale[t] = sc;
        }
        __syncthreads();   // weights visible
        if (act) {
            float sc = sh_scale[hd];
            acc.x *= sc; acc.y *= sc; acc.z *= sc; acc.w *= sc;
            #pragma unroll
            for (int e = 0; e < FCH; ++e) {
                float w = sh_w[e][hd];   // 0 for invalid tail edges
                acc.x = fmaf(w, vl[e].x, acc.x);
                acc.y = fmaf(w, vl[e].y, acc.y);
                acc.z = fmaf(w, vl[e].z, acc.z);
                acc.w = fmaf(w, vl[e].w, acc.w);
            }
        }
    }
    if (act) {
        float inv = 1.f / sh_den[hd];
        float4 bv = ((const float4*)gat_bias)[t];
        ushort4 oh, ol;
        float v;
        v = fmaxf(fmaf(acc.x, inv, bv.x), 0.f); bsplit(v, oh.x, ol.x);
        v = fmaxf(fmaf(acc.y, inv, bv.y), 0.f); bsplit(v, oh.y, ol.y);
        v = fmaxf(fmaf(acc.z, inv, bv.z), 0.f); bsplit(v, oh.z, ol.z);
        v = fmaxf(fmaf(acc.w, inv, bv.w), 0.f); bsplit(v, oh.w, ol.w);
        *(ushort4*)(g1h + (size_t)d * HCc + 4 * t) = oh;
        *(ushort4*)(g1l + (size_t)d * HCc + 4 * t) = ol;
    }
}

// GCN aggregate, register-batched: g2[d] = relu(dinv[d]*sum dinv[src]*hg[src]+b)
#define GCH 16
__global__ __launch_bounds__(256)
void gcn_kernel(const float* __restrict__ hg, const float* __restrict__ dinv,
                const int* __restrict__ elist, const int* __restrict__ off,
                const float* __restrict__ b_gcn, float* __restrict__ g2) {
    int d = blockIdx.x;
    int t = threadIdx.x;
    __shared__ int src_s[GCH];
    __shared__ float w_s[GCH];
    int e0 = off[d], e1 = off[d + 1];
    int cnt = e1 - e0;
    float di = dinv[d];
    bool act = t < 200;
    float4 acc = {0.f, 0.f, 0.f, 0.f};
    for (int base = 0; base < cnt; base += GCH) {
        int nc = min(GCH, cnt - base);
        if (t < GCH) {
            int s = elist[e0 + base + min(t, nc - 1)];
            src_s[t] = s;
            w_s[t] = (t < nc) ? dinv[s] : 0.f;
        }
        __syncthreads();
        if (act) {
            float4 vl[GCH];
            #pragma unroll
            for (int e = 0; e < GCH; ++e)
                vl[e] = ((const float4*)(hg + (size_t)src_s[e] * HCc))[t];
            #pragma unroll
            for (int e = 0; e < GCH; ++e) {
                float w = w_s[e];
                acc.x = fmaf(w, vl[e].x, acc.x);
                acc.y = fmaf(w, vl[e].y, acc.y);
                acc.z = fmaf(w, vl[e].z, acc.z);
                acc.w = fmaf(w, vl[e].w, acc.w);
            }
        }
        __syncthreads();
    }
    if (act) {
        float4 bv = ((const float4*)b_gcn)[t];
        float4 o;
        o.x = fmaxf(acc.x * di + bv.x, 0.f);
        o.y = fmaxf(acc.y * di + bv.y, 0.f);
        o.z = fmaxf(acc.z * di + bv.z, 0.f);
        o.w = fmaxf(acc.w * di + bv.w, 0.f);
        *(float4*)(g2 + (size_t)d * HCc + 4 * t) = o;
    }
}

// graph boundaries in sorted batch (lower bound per graph)
__global__ void bounds_kernel(const int* __restrict__ batch, int* __restrict__ starts) {
    int g = threadIdx.x;
    if (g <= Gg) {
        if (g == Gg) { starts[Gg] = Nn; return; }
        int lo = 0, hi = Nn;
        while (lo < hi) {
            int mid = (lo + hi) >> 1;
            if (batch[mid] < g) lo = mid + 1; else hi = mid;
        }
        starts[g] = lo;
    }
}

// ---- two-stage pool: node-sliced partials, then combine ----
#define PSL 4
__global__ __launch_bounds__(256)
void pool1_kernel(const float* __restrict__ g2, const float* __restrict__ fw,
                  const int* __restrict__ starts, float* __restrict__ pw,
                  float* __restrict__ pmean, float* __restrict__ pmax) {
    int g = blockIdx.x, s = blockIdx.y, t = threadIdx.x;
    int n0 = starts[g], n1 = starts[g + 1];
    int len = n1 - n0;
    int q0 = n0 + (int)(((long long)len * s) / PSL);
    int q1 = n0 + (int)(((long long)len * (s + 1)) / PSL);
    __shared__ float red[256];
    float wsum = 0.f;
    for (int n = q0 + t; n < q1; n += 256) wsum += fw[n];
    red[t] = wsum;
    __syncthreads();
    for (int ofs = 128; ofs > 0; ofs >>= 1) {
        if (t < ofs) red[t] += red[t + ofs];
        __syncthreads();
    }
    if (t == 0) pw[g * PSL + s] = red[0];
    if (t < 200) {
        float4 sum = {0.f, 0.f, 0.f, 0.f};
        float4 mx = {0.f, 0.f, 0.f, 0.f};
        for (int n = q0; n < q1; ++n) {
            float w = fw[n];
            float4 v = ((const float4*)(g2 + (size_t)n * HCc))[t];
            sum.x = fmaf(w, v.x, sum.x); sum.y = fmaf(w, v.y, sum.y);
            sum.z = fmaf(w, v.z, sum.z); sum.w = fmaf(w, v.w, sum.w);
            mx.x = fmaxf(mx.x, v.x); mx.y = fmaxf(mx.y, v.y);
            mx.z = fmaxf(mx.z, v.z); mx.w = fmaxf(mx.w, v.w);
        }
        size_t o = ((size_t)g * PSL + s) * HCc + 4 * t;
        *(float4*)(pmean + o) = sum;
        *(float4*)(pmax + o) = mx;
    }
}
__global__ __launch_bounds__(256)
void pool2_kernel(const float* __restrict__ pw, const float* __restrict__ pmean,
                  const float* __restrict__ pmax, float* __restrict__ gfeat) {
    int g = blockIdx.x, t = threadIdx.x;
    if (t >= 200) return;
    float wsg = 0.f;
    #pragma unroll
    for (int s = 0; s < PSL; ++s) wsg += pw[g * PSL + s];
    wsg = fmaxf(wsg, 1e-6f);
    float inv = 1.f / wsg;
    float4 sum = {0.f, 0.f, 0.f, 0.f};
    float4 mx = {0.f, 0.f, 0.f, 0.f};
    #pragma unroll
    for (int s = 0; s < PSL; ++s) {
        size_t o = ((size_t)g * PSL + s) * HCc + 4 * t;
        float4 a = *(const float4*)(pmean + o);
        float4 b = *(const float4*)(pmax + o);
        sum.x += a.x; sum.y += a.y; sum.z += a.z; sum.w += a.w;
        mx.x = fmaxf(mx.x, b.x); mx.y = fmaxf(mx.y, b.y);
        mx.z = fmaxf(mx.z, b.z); mx.w = fmaxf(mx.w, b.w);
    }
    float* gm = gfeat + (size_t)g * (2 * HCc);
    sum.x *= inv; sum.y *= inv; sum.z *= inv; sum.w *= inv;
    *(float4*)(gm + 4 * t) = sum;
    *(float4*)(gm + HCc + 4 * t) = mx;
}

// final MLP head: out = relu(relu(gfeat@W_fc + b_fc) @ W_out + b_out)
__global__ __launch_bounds__(128)
void head_kernel(const float* __restrict__ gfeat, const float* __restrict__ W_fc,
                 const float* __restrict__ b_fc, const float* __restrict__ W_out,
                 const float* __restrict__ b_out, float* __restrict__ out) {
    int g = blockIdx.x;
    int t = threadIdx.x;  // 128
    __shared__ float gf[2 * HCc];
    __shared__ float fc1[H2c];
    for (int i = t; i < 2 * HCc; i += 128) gf[i] = gfeat[(size_t)g * (2 * HCc) + i];
    __syncthreads();
    float a0 = 0.f, a1 = 0.f, a2 = 0.f, a3 = 0.f;
    for (int k = 0; k < 2 * HCc; k += 4) {
        a0 = fmaf(gf[k],     W_fc[(size_t)k * H2c + t], a0);
        a1 = fmaf(gf[k + 1], W_fc[(size_t)(k + 1) * H2c + t], a1);
        a2 = fmaf(gf[k + 2], W_fc[(size_t)(k + 2) * H2c + t], a2);
        a3 = fmaf(gf[k + 3], W_fc[(size_t)(k + 3) * H2c + t], a3);
    }
    fc1[t] = fmaxf(b_fc[t] + ((a0 + a1) + (a2 + a3)), 0.f);
    __syncthreads();
    if (t < OUTc) {
        float o = b_out[t];
        #pragma unroll 8
        for (int k = 0; k < H2c; ++k) o += fc1[k] * W_out[k * OUTc + t];
        out[g * OUTc + t] = fmaxf(o, 0.f);
    }
}

extern "C" void kernel_launch(void* const* d_in, const int* in_sizes, int n_in,
                              void* d_out, int out_size, void* d_ws, size_t ws_size,
                              hipStream_t stream) {
    (void)in_sizes; (void)n_in; (void)out_size; (void)ws_size;
    const float* x        = (const float*)d_in[0];
    const float* pe       = (const float*)d_in[1];
    const int*   eidx     = (const int*)d_in[2];
    const int*   batch    = (const int*)d_in[3];
    const float* fw       = (const float*)d_in[4];
    const float* W_pre    = (const float*)d_in[6];
    const float* b_pre    = (const float*)d_in[7];
    const float* W_l      = (const float*)d_in[8];
    const float* b_l      = (const float*)d_in[9];
    const float* W_r      = (const float*)d_in[10];
    const float* b_r      = (const float*)d_in[11];
    const float* att      = (const float*)d_in[12];
    const float* gat_bias = (const float*)d_in[13];
    const float* W_gcn    = (const float*)d_in[14];
    const float* b_gcn    = (const float*)d_in[15];
    const float* W_fc     = (const float*)d_in[16];
    const float* b_fc     = (const float*)d_in[17];
    const float* W_out    = (const float*)d_in[18];
    const float* b_out    = (const float*)d_in[19];
    float* out = (float*)d_out;

    // ---- workspace carving ----
    char* p = (char*)d_ws;
    auto alloc = [&](size_t bytes) {
        char* r = p;
        p += (bytes + 255) & ~(size_t)255;
        return r;
    };
    unsigned short* hh = (unsigned short*)alloc((size_t)Nn * Dd * 2 * 2);
    unsigned short* hl = hh + (size_t)Nn * Dd;
    float* bufA = (float*)alloc((size_t)Nn * HCc * 4);  // xl, later hg
    float* bufB = (float*)alloc((size_t)Nn * HCc * 4);  // xr, later g2
    float* bufC = (float*)alloc((size_t)Nn * HCc * 4);  // x splits, later g1 splits
    int*   cnt    = (int*)alloc((size_t)Nn * 4);
    int*   off    = (int*)alloc((size_t)(Nn + 1) * 4);
    int*   nxt    = (int*)alloc((size_t)Nn * 4);
    float* dinv   = (float*)alloc((size_t)Nn * 4);
    int*   elist  = (int*)alloc((size_t)ETot * 4);
    int*   starts = (int*)alloc((size_t)(Gg + 1) * 4);
    float* gfeat  = (float*)alloc((size_t)Gg * 2 * HCc * 4);
    int*   bsum   = (int*)alloc((size_t)NBLK * 4);
    float* pw     = (float*)alloc((size_t)Gg * PSL * 4);
    float* pmean  = (float*)alloc((size_t)Gg * PSL * HCc * 4);
    float* pmax   = (float*)alloc((size_t)Gg * PSL * HCc * 4);
    unsigned short* WpreTh = (unsigned short*)alloc((size_t)Ff * H1c * 2 * 2);
    unsigned short* WpreTl = WpreTh + (size_t)Ff * H1c;
    unsigned short* WlrTh  = (unsigned short*)alloc((size_t)Dd * 2 * HCc * 2 * 2);
    unsigned short* WlrTl  = WlrTh + (size_t)Dd * 2 * HCc;
    unsigned short* WgTh   = (unsigned short*)alloc((size_t)HCc * HCc * 2 * 2);
    unsigned short* WgTl   = WgTh + (size_t)HCc * HCc;

    // aliases (disjoint lifetimes within bufC)
    unsigned short* xh  = (unsigned short*)bufC;   // x splits: prep -> GEMM1
    unsigned short* xlo = xh + (size_t)Nn * Ff;
    unsigned short* g1h = (unsigned short*)bufC;   // g1 splits: fused agg -> GEMM4
    unsigned short* g1l = g1h + (size_t)Nn * HCc;

    // ---- CSR build ----
    hipMemsetAsync(cnt, 0, (size_t)Nn * 4, stream);
    count_kernel<<<(Ee + 255) / 256, 256, 0, stream>>>(eidx, cnt);
    scan1_kernel<<<NBLK, 256, 0, stream>>>(cnt, off, bsum);
    scan2_kernel<<<1, 64, 0, stream>>>(bsum);
    scan3_kernel<<<NBLK, 256, 0, stream>>>(cnt, off, nxt, dinv, bsum);
    scatter_kernel<<<(ETot + 255) / 256, 256, 0, stream>>>(eidx, nxt, elist);

    // ---- splits ----
    asplit_kernel<<<(Nn * Ff / 4 + 255) / 256, 256, 0, stream>>>(x, xh, xlo, Nn * Ff / 4);
    wsplit_kernel<<<(Ff * H1c + 255) / 256, 256, 0, stream>>>(W_pre, WpreTh, WpreTl, Ff, H1c);
    wsplit_kernel<<<(Dd * HCc + 255) / 256, 256, 0, stream>>>(W_l, WlrTh, WlrTl, Dd, HCc);
    wsplit_kernel<<<(Dd * HCc + 255) / 256, 256, 0, stream>>>(
        W_r, WlrTh + (size_t)HCc * Dd, WlrTl + (size_t)HCc * Dd, Dd, HCc);
    wsplit_kernel<<<(HCc * HCc + 255) / 256, 256, 0, stream>>>(W_gcn, WgTh, WgTl, HCc, HCc);

    // ---- GEMM1 (64x64 tile): h = relu(x@W_pre+b) -> h splits ----
    {
        dim3 grid((Nn + 63) / 64, (H1c + 63) / 64);
        gemm3_kernel<64, 64, 1><<<grid, 256, 0, stream>>>(
            xh, xlo, WpreTh, WpreTl, b_pre, nullptr, nullptr, nullptr, hh, hl,
            Nn, H1c, Ff, Ff, Dd, 1);
    }
    pe_copy_kernel<<<(Nn * PEc + 255) / 256, 256, 0, stream>>>(pe, hh, hl);

    // ---- merged GEMM2/3: [xl | xr] = h @ [W_l | W_r], cols<800 -> bufA else bufB ----
    {
        dim3 grid((Nn + 127) / 128, (2 * HCc + 127) / 128);
        gemm3_kernel<128, 128, 2><<<grid, 256, 0, stream>>>(
            hh, hl, WlrTh, WlrTl, b_l, b_r, bufA, bufB, nullptr, nullptr,
            Nn, 2 * HCc, Dd, Dd, HCc, 0);
    }

    // ---- FUSED GATv2 (single-read, 16-edge chunks) -> g1 (bufC) ----
    fused_gat_kernel<<<Nn, 256, 0, stream>>>(bufA, bufB, att, elist, off,
                                             gat_bias, g1h, g1l);

    // ---- GEMM4: hg = g1 @ W_gcn -> bufA (xl dead) ----
    {
        dim3 grid((Nn + 127) / 128, (HCc + 127) / 128);
        gemm3_kernel<128, 128, 0><<<grid, 256, 0, stream>>>(
            g1h, g1l, WgTh, WgTl, nullptr, nullptr, bufA, nullptr, nullptr, nullptr,
            Nn, HCc, HCc, HCc, HCc, 0);
    }
    // ---- GCN aggregate -> g2 (bufB, xr dead) ----
    gcn_kernel<<<Nn, 256, 0, stream>>>(bufA, dinv, elist, off, b_gcn, bufB);

    // ---- pooling (two-stage) + head ----
    bounds_kernel<<<1, 128, 0, stream>>>(batch, starts);
    {
        dim3 pg(Gg, PSL);
        pool1_kernel<<<pg, 256, 0, stream>>>(bufB, fw, starts, pw, pmean, pmax);
    }
    pool2_kernel<<<Gg, 256, 0, stream>>>(pw, pmean, pmax, gfeat);
    head_kernel<<<Gg, 128, 0, stream>>>(gfeat, W_fc, b_fc, W_out, b_out, out);
}

// Round 9
// 763.634 us; speedup vs baseline: 1.2906x; 1.0416x over previous
//
#include <hip/hip_runtime.h>
#include <hip/hip_bf16.h>

// Problem constants (fixed by reference)
#define Nn     20000
#define Ee     240000
#define Gg     64
#define Ff     768
#define H1c    128
#define PEc    32
#define Dd     160      // H1 + PE
#define HEADSc 5
#define HCc    800      // HEADS * D
#define H2c    128
#define OUTc   16
#define ETot   (Ee + Nn)  // edges + self loops = 260000
#define NEG_SLOPE_F 0.2f

typedef short bf16x8 __attribute__((ext_vector_type(8)));
typedef float f32x4 __attribute__((ext_vector_type(4)));
typedef float f32x16 __attribute__((ext_vector_type(16)));
typedef unsigned int u32;

// ---- bf16 split helpers (round-to-nearest-even) ----
__device__ __forceinline__ unsigned short bf_hi_rn(float v) {
    unsigned int u = __float_as_uint(v);
    return (unsigned short)((u + 0x7FFFu + ((u >> 16) & 1u)) >> 16);
}
__device__ __forceinline__ void bsplit(float v, unsigned short& h, unsigned short& l) {
    unsigned short hh = bf_hi_rn(v);
    float hf = __uint_as_float(((unsigned int)hh) << 16);
    l = bf_hi_rn(v - hf);
    h = hh;
}

// async global->LDS, 16 B per lane; LDS dest = wave-uniform base + lane*16
__device__ __forceinline__ void gl_lds16(const unsigned short* g, unsigned short* l) {
    __builtin_amdgcn_global_load_lds(
        (const __attribute__((address_space(1))) u32*)g,
        (__attribute__((address_space(3))) u32*)l, 16, 0, 0);
}

// ---------------------------------------------------------------------------
// Split fp32 array -> bf16 hi/lo arrays (same layout), vectorized by 4
// ---------------------------------------------------------------------------
__global__ void asplit_kernel(const float* __restrict__ A, unsigned short* __restrict__ Ah,
                              unsigned short* __restrict__ Al, int total4) {
    int i = blockIdx.x * 256 + threadIdx.x;
    if (i < total4) {
        float4 v = ((const float4*)A)[i];
        ushort4 h4, l4;
        bsplit(v.x, h4.x, l4.x);
        bsplit(v.y, h4.y, l4.y);
        bsplit(v.z, h4.z, l4.z);
        bsplit(v.w, h4.w, l4.w);
        ((ushort4*)Ah)[i] = h4;
        ((ushort4*)Al)[i] = l4;
    }
}

// Weight transpose + split: W[K][N] fp32 -> Wh/Wl[N][K] bf16
__global__ void wsplit_kernel(const float* __restrict__ W, unsigned short* __restrict__ Wh,
                              unsigned short* __restrict__ Wl, int K, int N) {
    int i = blockIdx.x * 256 + threadIdx.x;
    if (i < K * N) {
        int k = i / N, n = i % N;
        unsigned short h, l;
        bsplit(W[i], h, l);
        Wh[(size_t)n * K + k] = h;
        Wl[(size_t)n * K + k] = l;
    }
}

// ---------------------------------------------------------------------------
// bf16x3 MFMA GEMM on v_mfma_f32_32x32x16_bf16 (2382 TF shape).
// A hi/lo row-major [M][lda]; B TRANSPOSED hi/lo [N][K].
// Wave computes (BM/2)x(BN/2) via 32x32 tiles; per K-chunk of 32: 2 k-steps.
// OUT_MODE 0: fp32 C; 1: bf16 hi/lo split out; 2: dual fp32 dest, split @ col 800.
// ---------------------------------------------------------------------------
#define KCHUNK 32

template<int ROWS>
__device__ __forceinline__ void stage_tile(const unsigned short* __restrict__ gsrc, int ld,
                                           int row0, int maxRow, int k0,
                                           unsigned short* lbuf, int wave, int lane) {
    #pragma unroll
    for (int p = 0; p < ROWS / 64; ++p) {
        int rb = wave * 16 + p * 64;
        int r = rb + (lane >> 2);
        int gr = min(row0 + r, maxRow);
        const unsigned short* g = gsrc + (size_t)gr * ld + k0 + (lane & 3) * 8;
        gl_lds16(g, lbuf + rb * 32);
    }
}

template<int BM, int BN, int OUT_MODE>
__global__ __launch_bounds__(256)
void gemm3_kernel(const unsigned short* __restrict__ Ah, const unsigned short* __restrict__ Al,
                  const unsigned short* __restrict__ Bh, const unsigned short* __restrict__ Bl,
                  const float* __restrict__ bias, const float* __restrict__ bias2,
                  float* __restrict__ C, float* __restrict__ C2,
                  unsigned short* __restrict__ Ch, unsigned short* __restrict__ Cl,
                  int M, int N, int K, int lda, int ldc, int relu) {
    constexpr int TM = BM / 64;   // 32x32 tiles per wave in m
    constexpr int TN = BN / 64;
    __shared__ __attribute__((aligned(16))) unsigned short As_h[BM * 32];
    __shared__ __attribute__((aligned(16))) unsigned short As_l[BM * 32];
    __shared__ __attribute__((aligned(16))) unsigned short Bs_h[BN * 32];
    __shared__ __attribute__((aligned(16))) unsigned short Bs_l[BN * 32];

    int tid = threadIdx.x;
    int m0 = blockIdx.x * BM, n0 = blockIdx.y * BN;
    int wave = tid >> 6, lane = tid & 63;
    int wm = (wave >> 1) * (32 * TM);
    int wn = (wave & 1) * (32 * TN);
    int fr = lane & 31;            // m (or n) within 32-tile
    int fq = (lane >> 5) * 8;      // k sub-offset within 16

    f32x16 acc[TM][TN] = {};

    for (int k0 = 0; k0 < K; k0 += KCHUNK) {
        stage_tile<BM>(Ah, lda, m0, M - 1, k0, As_h, wave, lane);
        stage_tile<BM>(Al, lda, m0, M - 1, k0, As_l, wave, lane);
        stage_tile<BN>(Bh, K,   n0, N - 1, k0, Bs_h, wave, lane);
        stage_tile<BN>(Bl, K,   n0, N - 1, k0, Bs_l, wave, lane);
        __syncthreads();

        bf16x8 a_h[TM][2], a_l[TM][2], b_h[TN][2], b_l[TN][2];
        #pragma unroll
        for (int i = 0; i < TM; ++i) {
            #pragma unroll
            for (int s = 0; s < 2; ++s) {
                a_h[i][s] = *(const bf16x8*)&As_h[(wm + i * 32 + fr) * 32 + s * 16 + fq];
                a_l[i][s] = *(const bf16x8*)&As_l[(wm + i * 32 + fr) * 32 + s * 16 + fq];
            }
        }
        #pragma unroll
        for (int j = 0; j < TN; ++j) {
            #pragma unroll
            for (int s = 0; s < 2; ++s) {
                b_h[j][s] = *(const bf16x8*)&Bs_h[(wn + j * 32 + fr) * 32 + s * 16 + fq];
                b_l[j][s] = *(const bf16x8*)&Bs_l[(wn + j * 32 + fr) * 32 + s * 16 + fq];
            }
        }
        #pragma unroll
        for (int j = 0; j < TN; ++j) {
            #pragma unroll
            for (int i = 0; i < TM; ++i) {
                #pragma unroll
                for (int s = 0; s < 2; ++s) {
                    acc[i][j] = __builtin_amdgcn_mfma_f32_32x32x16_bf16(a_h[i][s], b_h[j][s], acc[i][j], 0, 0, 0);
                    acc[i][j] = __builtin_amdgcn_mfma_f32_32x32x16_bf16(a_h[i][s], b_l[j][s], acc[i][j], 0, 0, 0);
                    acc[i][j] = __builtin_amdgcn_mfma_f32_32x32x16_bf16(a_l[i][s], b_h[j][s], acc[i][j], 0, 0, 0);
                }
            }
        }
        __syncthreads();
    }

    // epilogue: C/D 32x32 layout col=lane&31, row=(reg&3)+8*(reg>>2)+4*(lane>>5)
    int cc = lane & 31;
    int rq = 4 * (lane >> 5);
    #pragma unroll
    for (int i = 0; i < TM; ++i) {
        #pragma unroll
        for (int j = 0; j < TN; ++j) {
            int c = n0 + wn + j * 32 + cc;
            if (c >= N) continue;
            float bv;
            if (OUT_MODE == 2) bv = (c < HCc) ? bias[c] : bias2[c - HCc];
            else bv = bias ? bias[c] : 0.f;
            #pragma unroll
            for (int reg = 0; reg < 16; ++reg) {
                int r = m0 + wm + i * 32 + (reg & 3) + 8 * (reg >> 2) + rq;
                if (r >= M) continue;
                float v = acc[i][j][reg] + bv;
                if (relu) v = fmaxf(v, 0.f);
                if (OUT_MODE == 0) {
                    C[(size_t)r * ldc + c] = v;
                } else if (OUT_MODE == 2) {
                    if (c < HCc) C[(size_t)r * HCc + c] = v;
                    else         C2[(size_t)r * HCc + (c - HCc)] = v;
                } else {
                    unsigned short hh, ll;
                    bsplit(v, hh, ll);
                    Ch[(size_t)r * ldc + c] = hh;
                    Cl[(size_t)r * ldc + c] = ll;
                }
            }
        }
    }
}

// copy pe_enc into h splits cols [128:160)
__global__ void pe_copy_kernel(const float* __restrict__ pe, unsigned short* __restrict__ hh,
                               unsigned short* __restrict__ hl) {
    int i = blockIdx.x * 256 + threadIdx.x;
    if (i < Nn * PEc) {
        int n = i / PEc, j = i % PEc;
        unsigned short h, l;
        bsplit(pe[i], h, l);
        hh[(size_t)n * Dd + H1c + j] = h;
        hl[(size_t)n * Dd + H1c + j] = l;
    }
}

// count in-degree (real edges only)
__global__ void count_kernel(const int* __restrict__ eidx, int* __restrict__ cnt) {
    int e = blockIdx.x * 256 + threadIdx.x;
    if (e < Ee) atomicAdd(&cnt[eidx[Ee + e]], 1);
}

// ---- multi-block exclusive scan over (cnt[i]+1) ----
#define NBLK 79  // ceil(20000/256)
__global__ void scan1_kernel(const int* __restrict__ cnt, int* __restrict__ off,
                             int* __restrict__ bsum) {
    __shared__ int sh[256];
    int t = threadIdx.x, i = blockIdx.x * 256 + t;
    int v = (i < Nn) ? (cnt[i] + 1) : 0;
    sh[t] = v;
    __syncthreads();
    for (int ofs = 1; ofs < 256; ofs <<= 1) {
        int add = (t >= ofs) ? sh[t - ofs] : 0;
        __syncthreads();
        sh[t] += add;
        __syncthreads();
    }
    if (i < Nn) off[i] = sh[t] - v;
    if (t == 255) bsum[blockIdx.x] = sh[255];
}
__global__ void scan2_kernel(int* __restrict__ bsum) {
    if (threadIdx.x == 0) {
        int acc = 0;
        for (int b = 0; b < NBLK; ++b) { int v = bsum[b]; bsum[b] = acc; acc += v; }
    }
}
__global__ void scan3_kernel(const int* __restrict__ cnt, int* __restrict__ off,
                             int* __restrict__ nxt, float* __restrict__ dinv,
                             const int* __restrict__ bsum) {
    int i = blockIdx.x * 256 + threadIdx.x;
    if (i < Nn) {
        int o = off[i] + bsum[blockIdx.x];
        off[i] = o;
        nxt[i] = o;
        dinv[i] = rsqrtf((float)(cnt[i] + 1));
    }
    if (i == 0) off[Nn] = ETot;
}

// scatter edges (and self loops) into CSR by dst
__global__ void scatter_kernel(const int* __restrict__ eidx, int* __restrict__ nxt,
                               int* __restrict__ elist) {
    int e = blockIdx.x * 256 + threadIdx.x;
    if (e < ETot) {
        int s, d;
        if (e < Ee) { s = eidx[e]; d = eidx[Ee + e]; }
        else        { s = e - Ee; d = s; }
        int slot = atomicAdd(&nxt[d], 1);
        elist[slot] = s;
    }
}

// ---------------------------------------------------------------------------
// FUSED GATv2, single-read register version (16-edge chunks, float4 reduce).
// ---------------------------------------------------------------------------
#define FCH 16
__global__ __launch_bounds__(256)
void fused_gat_kernel(const float* __restrict__ xl, const float* __restrict__ xr,
                      const float* __restrict__ att, const int* __restrict__ elist,
                      const int* __restrict__ off, const float* __restrict__ gat_bias,
                      unsigned short* __restrict__ g1h, unsigned short* __restrict__ g1l) {
    int d = blockIdx.x;
    int t = threadIdx.x;
    __shared__ __attribute__((aligned(16))) float sh_red[FCH][200];
    __shared__ float sh_sc[FCH][HEADSc];
    __shared__ float sh_w[FCH][HEADSc];
    __shared__ float sh_scale[HEADSc], sh_m[HEADSc], sh_den[HEADSc];
    __shared__ int sh_src[FCH];
    int e0 = off[d], e1 = off[d + 1];
    int cnt = e1 - e0;
    bool act = t < 200;
    int hd = act ? (t / 40) : 0;
    float4 vr = {0.f, 0.f, 0.f, 0.f}, va = {0.f, 0.f, 0.f, 0.f};
    if (act) {
        vr = ((const float4*)(xr + (size_t)d * HCc))[t];
        va = ((const float4*)att)[t];
    }
    if (t < HEADSc) { sh_m[t] = -1e30f; sh_den[t] = 0.f; }
    float4 acc = {0.f, 0.f, 0.f, 0.f};

    for (int base = 0; base < cnt; base += FCH) {
        int nc = min(FCH, cnt - base);
        if (t < FCH) sh_src[t] = elist[e0 + base + min(t, nc - 1)];
        __syncthreads();   // src visible (also fences prev chunk's sh_w reads)
        float4 vl[FCH];
        if (act) {
            #pragma unroll
            for (int e = 0; e < FCH; ++e)
                vl[e] = ((const float4*)(xl + (size_t)sh_src[e] * HCc))[t];
            #pragma unroll
            for (int e = 0; e < FCH; ++e) {
                float p = 0.f, m, lm;
                m = vl[e].x + vr.x; lm = fmaxf(m, 0.2f * m); p = fmaf(lm, va.x, p);
                m = vl[e].y + vr.y; lm = fmaxf(m, 0.2f * m); p = fmaf(lm, va.y, p);
                m = vl[e].z + vr.z; lm = fmaxf(m, 0.2f * m); p = fmaf(lm, va.z, p);
                m = vl[e].w + vr.w; lm = fmaxf(m, 0.2f * m); p = fmaf(lm, va.w, p);
                sh_red[e][t] = p;
            }
        }
        __syncthreads();   // partials visible
        if (t < 40) {      // two (edge,head) pairs per thread — all wave 0
            int e = t & 7, h = t >> 3;
            const float4* p0 = (const float4*)&sh_red[e][h * 40];
            const float4* p1 = (const float4*)&sh_red[e + 8][h * 40];
            float4 s4a = {0.f, 0.f, 0.f, 0.f}, s4b = {0.f, 0.f, 0.f, 0.f};
            #pragma unroll
            for (int k = 0; k < 10; ++k) {
                float4 u = p0[k], w = p1[k];
                s4a.x += u.x; s4a.y += u.y; s4a.z += u.z; s4a.w += u.w;
                s4b.x += w.x; s4b.y += w.y; s4b.z += w.z; s4b.w += w.w;
            }
            float s0 = (s4a.x + s4a.y) + (s4a.z + s4a.w);
            float s1 = (s4b.x + s4b.y) + (s4b.z + s4b.w);
            sh_sc[e][h]     = (e < nc)     ? s0 : -1e30f;
            sh_sc[e + 8][h] = (e + 8 < nc) ? s1 : -1e30f;
        }
        if (t < HEADSc) {  // same wave: LDS ops stay ordered
            float mo = sh_m[t];
            float mn = mo;
            #pragma unroll
            for (int e = 0; e < FCH; ++e) mn = fmaxf(mn, sh_sc[e][t]);
            float sc = __expf(mo - mn);
            float den = sh_den[t] * sc;
            #pragma unroll
            for (int e = 0; e < FCH; ++e) {
                float w = __expf(sh_sc[e][t] - mn);
                sh_w[e][t] = w;
                den += w;
            }
            sh_den[t] = den;
            sh_m[t] = mn;
            sh_scale[t] = sc;
        }
        __syncthreads();   // weights visible
        if (act) {
            float sc = sh_scale[hd];
            acc.x *= sc; acc.y *= sc; acc.z *= sc; acc.w *= sc;
            #pragma unroll
            for (int e = 0; e < FCH; ++e) {
                float w = sh_w[e][hd];   // 0 for invalid tail edges
                acc.x = fmaf(w, vl[e].x, acc.x);
                acc.y = fmaf(w, vl[e].y, acc.y);
                acc.z = fmaf(w, vl[e].z, acc.z);
                acc.w = fmaf(w, vl[e].w, acc.w);
            }
        }
    }
    if (act) {
        float inv = 1.f / sh_den[hd];
        float4 bv = ((const float4*)gat_bias)[t];
        ushort4 oh, ol;
        float v;
        v = fmaxf(fmaf(acc.x, inv, bv.x), 0.f); bsplit(v, oh.x, ol.x);
        v = fmaxf(fmaf(acc.y, inv, bv.y), 0.f); bsplit(v, oh.y, ol.y);
        v = fmaxf(fmaf(acc.z, inv, bv.z), 0.f); bsplit(v, oh.z, ol.z);
        v = fmaxf(fmaf(acc.w, inv, bv.w), 0.f); bsplit(v, oh.w, ol.w);
        *(ushort4*)(g1h + (size_t)d * HCc + 4 * t) = oh;
        *(ushort4*)(g1l + (size_t)d * HCc + 4 * t) = ol;
    }
}

// GCN aggregate, register-batched: g2[d] = relu(dinv[d]*sum dinv[src]*hg[src]+b)
#define GCH 16
__global__ __launch_bounds__(256)
void gcn_kernel(const float* __restrict__ hg, const float* __restrict__ dinv,
                const int* __restrict__ elist, const int* __restrict__ off,
                const float* __restrict__ b_gcn, float* __restrict__ g2) {
    int d = blockIdx.x;
    int t = threadIdx.x;
    __shared__ int src_s[GCH];
    __shared__ float w_s[GCH];
    int e0 = off[d], e1 = off[d + 1];
    int cnt = e1 - e0;
    float di = dinv[d];
    bool act = t < 200;
    float4 acc = {0.f, 0.f, 0.f, 0.f};
    for (int base = 0; base < cnt; base += GCH) {
        int nc = min(GCH, cnt - base);
        if (t < GCH) {
            int s = elist[e0 + base + min(t, nc - 1)];
            src_s[t] = s;
            w_s[t] = (t < nc) ? dinv[s] : 0.f;
        }
        __syncthreads();
        if (act) {
            float4 vl[GCH];
            #pragma unroll
            for (int e = 0; e < GCH; ++e)
                vl[e] = ((const float4*)(hg + (size_t)src_s[e] * HCc))[t];
            #pragma unroll
            for (int e = 0; e < GCH; ++e) {
                float w = w_s[e];
                acc.x = fmaf(w, vl[e].x, acc.x);
                acc.y = fmaf(w, vl[e].y, acc.y);
                acc.z = fmaf(w, vl[e].z, acc.z);
                acc.w = fmaf(w, vl[e].w, acc.w);
            }
        }
        __syncthreads();
    }
    if (act) {
        float4 bv = ((const float4*)b_gcn)[t];
        float4 o;
        o.x = fmaxf(acc.x * di + bv.x, 0.f);
        o.y = fmaxf(acc.y * di + bv.y, 0.f);
        o.z = fmaxf(acc.z * di + bv.z, 0.f);
        o.w = fmaxf(acc.w * di + bv.w, 0.f);
        *(float4*)(g2 + (size_t)d * HCc + 4 * t) = o;
    }
}

// graph boundaries in sorted batch (lower bound per graph)
__global__ void bounds_kernel(const int* __restrict__ batch, int* __restrict__ starts) {
    int g = threadIdx.x;
    if (g <= Gg) {
        if (g == Gg) { starts[Gg] = Nn; return; }
        int lo = 0, hi = Nn;
        while (lo < hi) {
            int mid = (lo + hi) >> 1;
            if (batch[mid] < g) lo = mid + 1; else hi = mid;
        }
        starts[g] = lo;
    }
}

// ---- two-stage pool: node-sliced partials, then combine ----
#define PSL 4
__global__ __launch_bounds__(256)
void pool1_kernel(const float* __restrict__ g2, const float* __restrict__ fw,
                  const int* __restrict__ starts, float* __restrict__ pw,
                  float* __restrict__ pmean, float* __restrict__ pmax) {
    int g = blockIdx.x, s = blockIdx.y, t = threadIdx.x;
    int n0 = starts[g], n1 = starts[g + 1];
    int len = n1 - n0;
    int q0 = n0 + (int)(((long long)len * s) / PSL);
    int q1 = n0 + (int)(((long long)len * (s + 1)) / PSL);
    __shared__ float red[256];
    float wsum = 0.f;
    for (int n = q0 + t; n < q1; n += 256) wsum += fw[n];
    red[t] = wsum;
    __syncthreads();
    for (int ofs = 128; ofs > 0; ofs >>= 1) {
        if (t < ofs) red[t] += red[t + ofs];
        __syncthreads();
    }
    if (t == 0) pw[g * PSL + s] = red[0];
    if (t < 200) {
        float4 sum = {0.f, 0.f, 0.f, 0.f};
        float4 mx = {0.f, 0.f, 0.f, 0.f};
        for (int n = q0; n < q1; ++n) {
            float w = fw[n];
            float4 v = ((const float4*)(g2 + (size_t)n * HCc))[t];
            sum.x = fmaf(w, v.x, sum.x); sum.y = fmaf(w, v.y, sum.y);
            sum.z = fmaf(w, v.z, sum.z); sum.w = fmaf(w, v.w, sum.w);
            mx.x = fmaxf(mx.x, v.x); mx.y = fmaxf(mx.y, v.y);
            mx.z = fmaxf(mx.z, v.z); mx.w = fmaxf(mx.w, v.w);
        }
        size_t o = ((size_t)g * PSL + s) * HCc + 4 * t;
        *(float4*)(pmean + o) = sum;
        *(float4*)(pmax + o) = mx;
    }
}
__global__ __launch_bounds__(256)
void pool2_kernel(const float* __restrict__ pw, const float* __restrict__ pmean,
                  const float* __restrict__ pmax, float* __restrict__ gfeat) {
    int g = blockIdx.x, t = threadIdx.x;
    if (t >= 200) return;
    float wsg = 0.f;
    #pragma unroll
    for (int s = 0; s < PSL; ++s) wsg += pw[g * PSL + s];
    wsg = fmaxf(wsg, 1e-6f);
    float inv = 1.f / wsg;
    float4 sum = {0.f, 0.f, 0.f, 0.f};
    float4 mx = {0.f, 0.f, 0.f, 0.f};
    #pragma unroll
    for (int s = 0; s < PSL; ++s) {
        size_t o = ((size_t)g * PSL + s) * HCc + 4 * t;
        float4 a = *(const float4*)(pmean + o);
        float4 b = *(const float4*)(pmax + o);
        sum.x += a.x; sum.y += a.y; sum.z += a.z; sum.w += a.w;
        mx.x = fmaxf(mx.x, b.x); mx.y = fmaxf(mx.y, b.y);
        mx.z = fmaxf(mx.z, b.z); mx.w = fmaxf(mx.w, b.w);
    }
    float* gm = gfeat + (size_t)g * (2 * HCc);
    sum.x *= inv; sum.y *= inv; sum.z *= inv; sum.w *= inv;
    *(float4*)(gm + 4 * t) = sum;
    *(float4*)(gm + HCc + 4 * t) = mx;
}

// final MLP head: out = relu(relu(gfeat@W_fc + b_fc) @ W_out + b_out)
__global__ __launch_bounds__(128)
void head_kernel(const float* __restrict__ gfeat, const float* __restrict__ W_fc,
                 const float* __restrict__ b_fc, const float* __restrict__ W_out,
                 const float* __restrict__ b_out, float* __restrict__ out) {
    int g = blockIdx.x;
    int t = threadIdx.x;  // 128
    __shared__ float gf[2 * HCc];
    __shared__ float fc1[H2c];
    for (int i = t; i < 2 * HCc; i += 128) gf[i] = gfeat[(size_t)g * (2 * HCc) + i];
    __syncthreads();
    float a0 = 0.f, a1 = 0.f, a2 = 0.f, a3 = 0.f;
    for (int k = 0; k < 2 * HCc; k += 4) {
        a0 = fmaf(gf[k],     W_fc[(size_t)k * H2c + t], a0);
        a1 = fmaf(gf[k + 1], W_fc[(size_t)(k + 1) * H2c + t], a1);
        a2 = fmaf(gf[k + 2], W_fc[(size_t)(k + 2) * H2c + t], a2);
        a3 = fmaf(gf[k + 3], W_fc[(size_t)(k + 3) * H2c + t], a3);
    }
    fc1[t] = fmaxf(b_fc[t] + ((a0 + a1) + (a2 + a3)), 0.f);
    __syncthreads();
    if (t < OUTc) {
        float o = b_out[t];
        #pragma unroll 8
        for (int k = 0; k < H2c; ++k) o += fc1[k] * W_out[k * OUTc + t];
        out[g * OUTc + t] = fmaxf(o, 0.f);
    }
}

extern "C" void kernel_launch(void* const* d_in, const int* in_sizes, int n_in,
                              void* d_out, int out_size, void* d_ws, size_t ws_size,
                              hipStream_t stream) {
    (void)in_sizes; (void)n_in; (void)out_size; (void)ws_size;
    const float* x        = (const float*)d_in[0];
    const float* pe       = (const float*)d_in[1];
    const int*   eidx     = (const int*)d_in[2];
    const int*   batch    = (const int*)d_in[3];
    const float* fw       = (const float*)d_in[4];
    const float* W_pre    = (const float*)d_in[6];
    const float* b_pre    = (const float*)d_in[7];
    const float* W_l      = (const float*)d_in[8];
    const float* b_l      = (const float*)d_in[9];
    const float* W_r      = (const float*)d_in[10];
    const float* b_r      = (const float*)d_in[11];
    const float* att      = (const float*)d_in[12];
    const float* gat_bias = (const float*)d_in[13];
    const float* W_gcn    = (const float*)d_in[14];
    const float* b_gcn    = (const float*)d_in[15];
    const float* W_fc     = (const float*)d_in[16];
    const float* b_fc     = (const float*)d_in[17];
    const float* W_out    = (const float*)d_in[18];
    const float* b_out    = (const float*)d_in[19];
    float* out = (float*)d_out;

    // ---- workspace carving ----
    char* p = (char*)d_ws;
    auto alloc = [&](size_t bytes) {
        char* r = p;
        p += (bytes + 255) & ~(size_t)255;
        return r;
    };
    unsigned short* hh = (unsigned short*)alloc((size_t)Nn * Dd * 2 * 2);
    unsigned short* hl = hh + (size_t)Nn * Dd;
    float* bufA = (float*)alloc((size_t)Nn * HCc * 4);  // xl, later hg
    float* bufB = (float*)alloc((size_t)Nn * HCc * 4);  // xr, later g2
    float* bufC = (float*)alloc((size_t)Nn * HCc * 4);  // x splits, later g1 splits
    int*   cnt    = (int*)alloc((size_t)Nn * 4);
    int*   off    = (int*)alloc((size_t)(Nn + 1) * 4);
    int*   nxt    = (int*)alloc((size_t)Nn * 4);
    float* dinv   = (float*)alloc((size_t)Nn * 4);
    int*   elist  = (int*)alloc((size_t)ETot * 4);
    int*   starts = (int*)alloc((size_t)(Gg + 1) * 4);
    float* gfeat  = (float*)alloc((size_t)Gg * 2 * HCc * 4);
    int*   bsum   = (int*)alloc((size_t)NBLK * 4);
    float* pw     = (float*)alloc((size_t)Gg * PSL * 4);
    float* pmean  = (float*)alloc((size_t)Gg * PSL * HCc * 4);
    float* pmax   = (float*)alloc((size_t)Gg * PSL * HCc * 4);
    unsigned short* WpreTh = (unsigned short*)alloc((size_t)Ff * H1c * 2 * 2);
    unsigned short* WpreTl = WpreTh + (size_t)Ff * H1c;
    unsigned short* WlrTh  = (unsigned short*)alloc((size_t)Dd * 2 * HCc * 2 * 2);
    unsigned short* WlrTl  = WlrTh + (size_t)Dd * 2 * HCc;
    unsigned short* WgTh   = (unsigned short*)alloc((size_t)HCc * HCc * 2 * 2);
    unsigned short* WgTl   = WgTh + (size_t)HCc * HCc;

    // aliases (disjoint lifetimes within bufC)
    unsigned short* xh  = (unsigned short*)bufC;   // x splits: prep -> GEMM1
    unsigned short* xlo = xh + (size_t)Nn * Ff;
    unsigned short* g1h = (unsigned short*)bufC;   // g1 splits: fused agg -> GEMM4
    unsigned short* g1l = g1h + (size_t)Nn * HCc;

    // ---- CSR build ----
    hipMemsetAsync(cnt, 0, (size_t)Nn * 4, stream);
    count_kernel<<<(Ee + 255) / 256, 256, 0, stream>>>(eidx, cnt);
    scan1_kernel<<<NBLK, 256, 0, stream>>>(cnt, off, bsum);
    scan2_kernel<<<1, 64, 0, stream>>>(bsum);
    scan3_kernel<<<NBLK, 256, 0, stream>>>(cnt, off, nxt, dinv, bsum);
    scatter_kernel<<<(ETot + 255) / 256, 256, 0, stream>>>(eidx, nxt, elist);

    // ---- splits ----
    asplit_kernel<<<(Nn * Ff / 4 + 255) / 256, 256, 0, stream>>>(x, xh, xlo, Nn * Ff / 4);
    wsplit_kernel<<<(Ff * H1c + 255) / 256, 256, 0, stream>>>(W_pre, WpreTh, WpreTl, Ff, H1c);
    wsplit_kernel<<<(Dd * HCc + 255) / 256, 256, 0, stream>>>(W_l, WlrTh, WlrTl, Dd, HCc);
    wsplit_kernel<<<(Dd * HCc + 255) / 256, 256, 0, stream>>>(
        W_r, WlrTh + (size_t)HCc * Dd, WlrTl + (size_t)HCc * Dd, Dd, HCc);
    wsplit_kernel<<<(HCc * HCc + 255) / 256, 256, 0, stream>>>(W_gcn, WgTh, WgTl, HCc, HCc);

    // ---- GEMM1 (64x64 tile): h = relu(x@W_pre+b) -> h splits ----
    {
        dim3 grid((Nn + 63) / 64, (H1c + 63) / 64);
        gemm3_kernel<64, 64, 1><<<grid, 256, 0, stream>>>(
            xh, xlo, WpreTh, WpreTl, b_pre, nullptr, nullptr, nullptr, hh, hl,
            Nn, H1c, Ff, Ff, Dd, 1);
    }
    pe_copy_kernel<<<(Nn * PEc + 255) / 256, 256, 0, stream>>>(pe, hh, hl);

    // ---- merged GEMM2/3: [xl | xr] = h @ [W_l | W_r], cols<800 -> bufA else bufB ----
    {
        dim3 grid((Nn + 127) / 128, (2 * HCc + 127) / 128);
        gemm3_kernel<128, 128, 2><<<grid, 256, 0, stream>>>(
            hh, hl, WlrTh, WlrTl, b_l, b_r, bufA, bufB, nullptr, nullptr,
            Nn, 2 * HCc, Dd, Dd, HCc, 0);
    }

    // ---- FUSED GATv2 (single-read, 16-edge chunks) -> g1 (bufC) ----
    fused_gat_kernel<<<Nn, 256, 0, stream>>>(bufA, bufB, att, elist, off,
                                             gat_bias, g1h, g1l);

    // ---- GEMM4: hg = g1 @ W_gcn -> bufA (xl dead) ----
    {
        dim3 grid((Nn + 127) / 128, (HCc + 127) / 128);
        gemm3_kernel<128, 128, 0><<<grid, 256, 0, stream>>>(
            g1h, g1l, WgTh, WgTl, nullptr, nullptr, bufA, nullptr, nullptr, nullptr,
            Nn, HCc, HCc, HCc, HCc, 0);
    }
    // ---- GCN aggregate -> g2 (bufB, xr dead) ----
    gcn_kernel<<<Nn, 256, 0, stream>>>(bufA, dinv, elist, off, b_gcn, bufB);

    // ---- pooling (two-stage) + head ----
    bounds_kernel<<<1, 128, 0, stream>>>(batch, starts);
    {
        dim3 pg(Gg, PSL);
        pool1_kernel<<<pg, 256, 0, stream>>>(bufB, fw, starts, pw, pmean, pmax);
    }
    pool2_kernel<<<Gg, 256, 0, stream>>>(pw, pmean, pmax, gfeat);
    head_kernel<<<Gg, 128, 0, stream>>>(gfeat, W_fc, b_fc, W_out, b_out, out);
}

// Round 10
// 750.020 us; speedup vs baseline: 1.3140x; 1.0182x over previous
//
#include <hip/hip_runtime.h>
#include <hip/hip_bf16.h>

// Problem constants (fixed by reference)
#define Nn     20000
#define Ee     240000
#define Gg     64
#define Ff     768
#define H1c    128
#define PEc    32
#define Dd     160      // H1 + PE
#define HEADSc 5
#define HCc    800      // HEADS * D
#define H2c    128
#define OUTc   16
#define ETot   (Ee + Nn)  // edges + self loops = 260000
#define NEG_SLOPE_F 0.2f

typedef short bf16x8 __attribute__((ext_vector_type(8)));
typedef float f32x4 __attribute__((ext_vector_type(4)));
typedef float f32x16 __attribute__((ext_vector_type(16)));
typedef unsigned int u32;

// ---- bf16 split helpers (round-to-nearest-even) ----
__device__ __forceinline__ unsigned short bf_hi_rn(float v) {
    unsigned int u = __float_as_uint(v);
    return (unsigned short)((u + 0x7FFFu + ((u >> 16) & 1u)) >> 16);
}
__device__ __forceinline__ void bsplit(float v, unsigned short& h, unsigned short& l) {
    unsigned short hh = bf_hi_rn(v);
    float hf = __uint_as_float(((unsigned int)hh) << 16);
    l = bf_hi_rn(v - hf);
    h = hh;
}

// async global->LDS, 16 B per lane; LDS dest = wave-uniform base + lane*16
__device__ __forceinline__ void gl_lds16(const unsigned short* g, unsigned short* l) {
    __builtin_amdgcn_global_load_lds(
        (const __attribute__((address_space(1))) u32*)g,
        (__attribute__((address_space(3))) u32*)l, 16, 0, 0);
}

// ---------------------------------------------------------------------------
// Split fp32 array -> bf16 hi/lo arrays (same layout), vectorized by 4
// ---------------------------------------------------------------------------
__global__ void asplit_kernel(const float* __restrict__ A, unsigned short* __restrict__ Ah,
                              unsigned short* __restrict__ Al, int total4) {
    int i = blockIdx.x * 256 + threadIdx.x;
    if (i < total4) {
        float4 v = ((const float4*)A)[i];
        ushort4 h4, l4;
        bsplit(v.x, h4.x, l4.x);
        bsplit(v.y, h4.y, l4.y);
        bsplit(v.z, h4.z, l4.z);
        bsplit(v.w, h4.w, l4.w);
        ((ushort4*)Ah)[i] = h4;
        ((ushort4*)Al)[i] = l4;
    }
}

// Weight transpose + split: W[K][N] fp32 -> Wh/Wl[N][K] bf16
__global__ void wsplit_kernel(const float* __restrict__ W, unsigned short* __restrict__ Wh,
                              unsigned short* __restrict__ Wl, int K, int N) {
    int i = blockIdx.x * 256 + threadIdx.x;
    if (i < K * N) {
        int k = i / N, n = i % N;
        unsigned short h, l;
        bsplit(W[i], h, l);
        Wh[(size_t)n * K + k] = h;
        Wl[(size_t)n * K + k] = l;
    }
}

// ---------------------------------------------------------------------------
// bf16x3 MFMA GEMM on v_mfma_f32_32x32x16_bf16 with XOR-swizzled LDS.
// LDS row = 32 bf16 (64 B) split into 4 sub-blocks of 16 B. LDS(r, sub)
// holds GLOBAL k-sub (sub ^ ((r>>1)&3)) — spreads banks to the 4-way
// minimum (rows r, r+2 inherently alias at 64 B row pitch).
// ---------------------------------------------------------------------------
#define KCHUNK 32

template<int ROWS>
__device__ __forceinline__ void stage_tile(const unsigned short* __restrict__ gsrc, int ld,
                                           int row0, int maxRow, int k0,
                                           unsigned short* lbuf, int wave, int lane) {
    #pragma unroll
    for (int p = 0; p < ROWS / 64; ++p) {
        int rb = wave * 16 + p * 64;
        int r = rb + (lane >> 2);
        int gr = min(row0 + r, maxRow);
        int ksub = (lane & 3) ^ ((r >> 1) & 3);   // source sub-block swizzle
        const unsigned short* g = gsrc + (size_t)gr * ld + k0 + ksub * 8;
        gl_lds16(g, lbuf + rb * 32);
    }
}

template<int BM, int BN, int OUT_MODE>
__global__ __launch_bounds__(256)
void gemm3_kernel(const unsigned short* __restrict__ Ah, const unsigned short* __restrict__ Al,
                  const unsigned short* __restrict__ Bh, const unsigned short* __restrict__ Bl,
                  const float* __restrict__ bias, const float* __restrict__ bias2,
                  float* __restrict__ C, float* __restrict__ C2,
                  unsigned short* __restrict__ Ch, unsigned short* __restrict__ Cl,
                  int M, int N, int K, int lda, int ldc, int relu) {
    constexpr int TM = BM / 64;   // 32x32 tiles per wave in m
    constexpr int TN = BN / 64;
    __shared__ __attribute__((aligned(16))) unsigned short As_h[BM * 32];
    __shared__ __attribute__((aligned(16))) unsigned short As_l[BM * 32];
    __shared__ __attribute__((aligned(16))) unsigned short Bs_h[BN * 32];
    __shared__ __attribute__((aligned(16))) unsigned short Bs_l[BN * 32];

    int tid = threadIdx.x;
    int m0 = blockIdx.x * BM, n0 = blockIdx.y * BN;
    int wave = tid >> 6, lane = tid & 63;
    int wm = (wave >> 1) * (32 * TM);
    int wn = (wave & 1) * (32 * TN);
    int fr = lane & 31;            // m (or n) within 32-tile
    int subhi = lane >> 5;         // k sub-block bit 0

    f32x16 acc[TM][TN] = {};

    for (int k0 = 0; k0 < K; k0 += KCHUNK) {
        stage_tile<BM>(Ah, lda, m0, M - 1, k0, As_h, wave, lane);
        stage_tile<BM>(Al, lda, m0, M - 1, k0, As_l, wave, lane);
        stage_tile<BN>(Bh, K,   n0, N - 1, k0, Bs_h, wave, lane);
        stage_tile<BN>(Bl, K,   n0, N - 1, k0, Bs_l, wave, lane);
        __syncthreads();

        bf16x8 a_h[TM][2], a_l[TM][2], b_h[TN][2], b_l[TN][2];
        #pragma unroll
        for (int i = 0; i < TM; ++i) {
            int ar = wm + i * 32 + fr;
            int asw = (ar >> 1) & 3;
            #pragma unroll
            for (int s = 0; s < 2; ++s) {
                int lsub = ((s << 1) | subhi) ^ asw;
                a_h[i][s] = *(const bf16x8*)&As_h[ar * 32 + lsub * 8];
                a_l[i][s] = *(const bf16x8*)&As_l[ar * 32 + lsub * 8];
            }
        }
        #pragma unroll
        for (int j = 0; j < TN; ++j) {
            int br = wn + j * 32 + fr;
            int bsw = (br >> 1) & 3;
            #pragma unroll
            for (int s = 0; s < 2; ++s) {
                int lsub = ((s << 1) | subhi) ^ bsw;
                b_h[j][s] = *(const bf16x8*)&Bs_h[br * 32 + lsub * 8];
                b_l[j][s] = *(const bf16x8*)&Bs_l[br * 32 + lsub * 8];
            }
        }
        #pragma unroll
        for (int j = 0; j < TN; ++j) {
            #pragma unroll
            for (int i = 0; i < TM; ++i) {
                #pragma unroll
                for (int s = 0; s < 2; ++s) {
                    acc[i][j] = __builtin_amdgcn_mfma_f32_32x32x16_bf16(a_h[i][s], b_h[j][s], acc[i][j], 0, 0, 0);
                    acc[i][j] = __builtin_amdgcn_mfma_f32_32x32x16_bf16(a_h[i][s], b_l[j][s], acc[i][j], 0, 0, 0);
                    acc[i][j] = __builtin_amdgcn_mfma_f32_32x32x16_bf16(a_l[i][s], b_h[j][s], acc[i][j], 0, 0, 0);
                }
            }
        }
        __syncthreads();
    }

    // epilogue: C/D 32x32 layout col=lane&31, row=(reg&3)+8*(reg>>2)+4*(lane>>5)
    int cc = lane & 31;
    int rq = 4 * (lane >> 5);
    #pragma unroll
    for (int i = 0; i < TM; ++i) {
        #pragma unroll
        for (int j = 0; j < TN; ++j) {
            int c = n0 + wn + j * 32 + cc;
            if (c >= N) continue;
            float bv;
            if (OUT_MODE == 2) bv = (c < HCc) ? bias[c] : bias2[c - HCc];
            else bv = bias ? bias[c] : 0.f;
            #pragma unroll
            for (int reg = 0; reg < 16; ++reg) {
                int r = m0 + wm + i * 32 + (reg & 3) + 8 * (reg >> 2) + rq;
                if (r >= M) continue;
                float v = acc[i][j][reg] + bv;
                if (relu) v = fmaxf(v, 0.f);
                if (OUT_MODE == 0) {
                    C[(size_t)r * ldc + c] = v;
                } else if (OUT_MODE == 2) {
                    if (c < HCc) C[(size_t)r * HCc + c] = v;
                    else         C2[(size_t)r * HCc + (c - HCc)] = v;
                } else {
                    unsigned short hh, ll;
                    bsplit(v, hh, ll);
                    Ch[(size_t)r * ldc + c] = hh;
                    Cl[(size_t)r * ldc + c] = ll;
                }
            }
        }
    }
}

// copy pe_enc into h splits cols [128:160)
__global__ void pe_copy_kernel(const float* __restrict__ pe, unsigned short* __restrict__ hh,
                               unsigned short* __restrict__ hl) {
    int i = blockIdx.x * 256 + threadIdx.x;
    if (i < Nn * PEc) {
        int n = i / PEc, j = i % PEc;
        unsigned short h, l;
        bsplit(pe[i], h, l);
        hh[(size_t)n * Dd + H1c + j] = h;
        hl[(size_t)n * Dd + H1c + j] = l;
    }
}

// count in-degree (real edges only)
__global__ void count_kernel(const int* __restrict__ eidx, int* __restrict__ cnt) {
    int e = blockIdx.x * 256 + threadIdx.x;
    if (e < Ee) atomicAdd(&cnt[eidx[Ee + e]], 1);
}

// ---- multi-block exclusive scan over (cnt[i]+1) ----
#define NBLK 79  // ceil(20000/256)
__global__ void scan1_kernel(const int* __restrict__ cnt, int* __restrict__ off,
                             int* __restrict__ bsum) {
    __shared__ int sh[256];
    int t = threadIdx.x, i = blockIdx.x * 256 + t;
    int v = (i < Nn) ? (cnt[i] + 1) : 0;
    sh[t] = v;
    __syncthreads();
    for (int ofs = 1; ofs < 256; ofs <<= 1) {
        int add = (t >= ofs) ? sh[t - ofs] : 0;
        __syncthreads();
        sh[t] += add;
        __syncthreads();
    }
    if (i < Nn) off[i] = sh[t] - v;
    if (t == 255) bsum[blockIdx.x] = sh[255];
}
__global__ void scan2_kernel(int* __restrict__ bsum) {
    if (threadIdx.x == 0) {
        int acc = 0;
        for (int b = 0; b < NBLK; ++b) { int v = bsum[b]; bsum[b] = acc; acc += v; }
    }
}
__global__ void scan3_kernel(const int* __restrict__ cnt, int* __restrict__ off,
                             int* __restrict__ nxt, float* __restrict__ dinv,
                             const int* __restrict__ bsum) {
    int i = blockIdx.x * 256 + threadIdx.x;
    if (i < Nn) {
        int o = off[i] + bsum[blockIdx.x];
        off[i] = o;
        nxt[i] = o;
        dinv[i] = rsqrtf((float)(cnt[i] + 1));
    }
    if (i == 0) off[Nn] = ETot;
}

// scatter edges (and self loops) into CSR by dst
__global__ void scatter_kernel(const int* __restrict__ eidx, int* __restrict__ nxt,
                               int* __restrict__ elist) {
    int e = blockIdx.x * 256 + threadIdx.x;
    if (e < ETot) {
        int s, d;
        if (e < Ee) { s = eidx[e]; d = eidx[Ee + e]; }
        else        { s = e - Ee; d = s; }
        int slot = atomicAdd(&nxt[d], 1);
        elist[slot] = s;
    }
}

// ---------------------------------------------------------------------------
// FUSED GATv2, single-read register version (16-edge chunks, float4 reduce).
// ---------------------------------------------------------------------------
#define FCH 16
__global__ __launch_bounds__(256)
void fused_gat_kernel(const float* __restrict__ xl, const float* __restrict__ xr,
                      const float* __restrict__ att, const int* __restrict__ elist,
                      const int* __restrict__ off, const float* __restrict__ gat_bias,
                      unsigned short* __restrict__ g1h, unsigned short* __restrict__ g1l) {
    int d = blockIdx.x;
    int t = threadIdx.x;
    __shared__ __attribute__((aligned(16))) float sh_red[FCH][200];
    __shared__ float sh_sc[FCH][HEADSc];
    __shared__ float sh_w[FCH][HEADSc];
    __shared__ float sh_scale[HEADSc], sh_m[HEADSc], sh_den[HEADSc];
    __shared__ int sh_src[FCH];
    int e0 = off[d], e1 = off[d + 1];
    int cnt = e1 - e0;
    bool act = t < 200;
    int hd = act ? (t / 40) : 0;
    float4 vr = {0.f, 0.f, 0.f, 0.f}, va = {0.f, 0.f, 0.f, 0.f};
    if (act) {
        vr = ((const float4*)(xr + (size_t)d * HCc))[t];
        va = ((const float4*)att)[t];
    }
    if (t < HEADSc) { sh_m[t] = -1e30f; sh_den[t] = 0.f; }
    float4 acc = {0.f, 0.f, 0.f, 0.f};

    for (int base = 0; base < cnt; base += FCH) {
        int nc = min(FCH, cnt - base);
        if (t < FCH) sh_src[t] = elist[e0 + base + min(t, nc - 1)];
        __syncthreads();   // src visible (also fences prev chunk's sh_w reads)
        float4 vl[FCH];
        if (act) {
            #pragma unroll
            for (int e = 0; e < FCH; ++e)
                vl[e] = ((const float4*)(xl + (size_t)sh_src[e] * HCc))[t];
            #pragma unroll
            for (int e = 0; e < FCH; ++e) {
                float p = 0.f, m, lm;
                m = vl[e].x + vr.x; lm = fmaxf(m, 0.2f * m); p = fmaf(lm, va.x, p);
                m = vl[e].y + vr.y; lm = fmaxf(m, 0.2f * m); p = fmaf(lm, va.y, p);
                m = vl[e].z + vr.z; lm = fmaxf(m, 0.2f * m); p = fmaf(lm, va.z, p);
                m = vl[e].w + vr.w; lm = fmaxf(m, 0.2f * m); p = fmaf(lm, va.w, p);
                sh_red[e][t] = p;
            }
        }
        __syncthreads();   // partials visible
        if (t < 40) {      // two (edge,head) pairs per thread — all wave 0
            int e = t & 7, h = t >> 3;
            const float4* p0 = (const float4*)&sh_red[e][h * 40];
            const float4* p1 = (const float4*)&sh_red[e + 8][h * 40];
            float4 s4a = {0.f, 0.f, 0.f, 0.f}, s4b = {0.f, 0.f, 0.f, 0.f};
            #pragma unroll
            for (int k = 0; k < 10; ++k) {
                float4 u = p0[k], w = p1[k];
                s4a.x += u.x; s4a.y += u.y; s4a.z += u.z; s4a.w += u.w;
                s4b.x += w.x; s4b.y += w.y; s4b.z += w.z; s4b.w += w.w;
            }
            float s0 = (s4a.x + s4a.y) + (s4a.z + s4a.w);
            float s1 = (s4b.x + s4b.y) + (s4b.z + s4b.w);
            sh_sc[e][h]     = (e < nc)     ? s0 : -1e30f;
            sh_sc[e + 8][h] = (e + 8 < nc) ? s1 : -1e30f;
        }
        if (t < HEADSc) {  // same wave: LDS ops stay ordered
            float mo = sh_m[t];
            float mn = mo;
            #pragma unroll
            for (int e = 0; e < FCH; ++e) mn = fmaxf(mn, sh_sc[e][t]);
            float sc = __expf(mo - mn);
            float den = sh_den[t] * sc;
            #pragma unroll
            for (int e = 0; e < FCH; ++e) {
                float w = __expf(sh_sc[e][t] - mn);
                sh_w[e][t] = w;
                den += w;
            }
            sh_den[t] = den;
            sh_m[t] = mn;
            sh_scale[t] = sc;
        }
        __syncthreads();   // weights visible
        if (act) {
            float sc = sh_scale[hd];
            acc.x *= sc; acc.y *= sc; acc.z *= sc; acc.w *= sc;
            #pragma unroll
            for (int e = 0; e < FCH; ++e) {
                float w = sh_w[e][hd];   // 0 for invalid tail edges
                acc.x = fmaf(w, vl[e].x, acc.x);
                acc.y = fmaf(w, vl[e].y, acc.y);
                acc.z = fmaf(w, vl[e].z, acc.z);
                acc.w = fmaf(w, vl[e].w, acc.w);
            }
        }
    }
    if (act) {
        float inv = 1.f / sh_den[hd];
        float4 bv = ((const float4*)gat_bias)[t];
        ushort4 oh, ol;
        float v;
        v = fmaxf(fmaf(acc.x, inv, bv.x), 0.f); bsplit(v, oh.x, ol.x);
        v = fmaxf(fmaf(acc.y, inv, bv.y), 0.f); bsplit(v, oh.y, ol.y);
        v = fmaxf(fmaf(acc.z, inv, bv.z), 0.f); bsplit(v, oh.z, ol.z);
        v = fmaxf(fmaf(acc.w, inv, bv.w), 0.f); bsplit(v, oh.w, ol.w);
        *(ushort4*)(g1h + (size_t)d * HCc + 4 * t) = oh;
        *(ushort4*)(g1l + (size_t)d * HCc + 4 * t) = ol;
    }
}

// GCN aggregate, register-batched: g2[d] = relu(dinv[d]*sum dinv[src]*hg[src]+b)
#define GCH 16
__global__ __launch_bounds__(256)
void gcn_kernel(const float* __restrict__ hg, const float* __restrict__ dinv,
                const int* __restrict__ elist, const int* __restrict__ off,
                const float* __restrict__ b_gcn, float* __restrict__ g2) {
    int d = blockIdx.x;
    int t = threadIdx.x;
    __shared__ int src_s[GCH];
    __shared__ float w_s[GCH];
    int e0 = off[d], e1 = off[d + 1];
    int cnt = e1 - e0;
    float di = dinv[d];
    bool act = t < 200;
    float4 acc = {0.f, 0.f, 0.f, 0.f};
    for (int base = 0; base < cnt; base += GCH) {
        int nc = min(GCH, cnt - base);
        if (t < GCH) {
            int s = elist[e0 + base + min(t, nc - 1)];
            src_s[t] = s;
            w_s[t] = (t < nc) ? dinv[s] : 0.f;
        }
        __syncthreads();
        if (act) {
            float4 vl[GCH];
            #pragma unroll
            for (int e = 0; e < GCH; ++e)
                vl[e] = ((const float4*)(hg + (size_t)src_s[e] * HCc))[t];
            #pragma unroll
            for (int e = 0; e < GCH; ++e) {
                float w = w_s[e];
                acc.x = fmaf(w, vl[e].x, acc.x);
                acc.y = fmaf(w, vl[e].y, acc.y);
                acc.z = fmaf(w, vl[e].z, acc.z);
                acc.w = fmaf(w, vl[e].w, acc.w);
            }
        }
        __syncthreads();
    }
    if (act) {
        float4 bv = ((const float4*)b_gcn)[t];
        float4 o;
        o.x = fmaxf(acc.x * di + bv.x, 0.f);
        o.y = fmaxf(acc.y * di + bv.y, 0.f);
        o.z = fmaxf(acc.z * di + bv.z, 0.f);
        o.w = fmaxf(acc.w * di + bv.w, 0.f);
        *(float4*)(g2 + (size_t)d * HCc + 4 * t) = o;
    }
}

// graph boundaries in sorted batch (lower bound per graph)
__global__ void bounds_kernel(const int* __restrict__ batch, int* __restrict__ starts) {
    int g = threadIdx.x;
    if (g <= Gg) {
        if (g == Gg) { starts[Gg] = Nn; return; }
        int lo = 0, hi = Nn;
        while (lo < hi) {
            int mid = (lo + hi) >> 1;
            if (batch[mid] < g) lo = mid + 1; else hi = mid;
        }
        starts[g] = lo;
    }
}

// ---- two-stage pool: node-sliced partials, then combine ----
#define PSL 4
__global__ __launch_bounds__(256)
void pool1_kernel(const float* __restrict__ g2, const float* __restrict__ fw,
                  const int* __restrict__ starts, float* __restrict__ pw,
                  float* __restrict__ pmean, float* __restrict__ pmax) {
    int g = blockIdx.x, s = blockIdx.y, t = threadIdx.x;
    int n0 = starts[g], n1 = starts[g + 1];
    int len = n1 - n0;
    int q0 = n0 + (int)(((long long)len * s) / PSL);
    int q1 = n0 + (int)(((long long)len * (s + 1)) / PSL);
    __shared__ float red[256];
    float wsum = 0.f;
    for (int n = q0 + t; n < q1; n += 256) wsum += fw[n];
    red[t] = wsum;
    __syncthreads();
    for (int ofs = 128; ofs > 0; ofs >>= 1) {
        if (t < ofs) red[t] += red[t + ofs];
        __syncthreads();
    }
    if (t == 0) pw[g * PSL + s] = red[0];
    if (t < 200) {
        float4 sum = {0.f, 0.f, 0.f, 0.f};
        float4 mx = {0.f, 0.f, 0.f, 0.f};
        for (int n = q0; n < q1; ++n) {
            float w = fw[n];
            float4 v = ((const float4*)(g2 + (size_t)n * HCc))[t];
            sum.x = fmaf(w, v.x, sum.x); sum.y = fmaf(w, v.y, sum.y);
            sum.z = fmaf(w, v.z, sum.z); sum.w = fmaf(w, v.w, sum.w);
            mx.x = fmaxf(mx.x, v.x); mx.y = fmaxf(mx.y, v.y);
            mx.z = fmaxf(mx.z, v.z); mx.w = fmaxf(mx.w, v.w);
        }
        size_t o = ((size_t)g * PSL + s) * HCc + 4 * t;
        *(float4*)(pmean + o) = sum;
        *(float4*)(pmax + o) = mx;
    }
}
__global__ __launch_bounds__(256)
void pool2_kernel(const float* __restrict__ pw, const float* __restrict__ pmean,
                  const float* __restrict__ pmax, float* __restrict__ gfeat) {
    int g = blockIdx.x, t = threadIdx.x;
    if (t >= 200) return;
    float wsg = 0.f;
    #pragma unroll
    for (int s = 0; s < PSL; ++s) wsg += pw[g * PSL + s];
    wsg = fmaxf(wsg, 1e-6f);
    float inv = 1.f / wsg;
    float4 sum = {0.f, 0.f, 0.f, 0.f};
    float4 mx = {0.f, 0.f, 0.f, 0.f};
    #pragma unroll
    for (int s = 0; s < PSL; ++s) {
        size_t o = ((size_t)g * PSL + s) * HCc + 4 * t;
        float4 a = *(const float4*)(pmean + o);
        float4 b = *(const float4*)(pmax + o);
        sum.x += a.x; sum.y += a.y; sum.z += a.z; sum.w += a.w;
        mx.x = fmaxf(mx.x, b.x); mx.y = fmaxf(mx.y, b.y);
        mx.z = fmaxf(mx.z, b.z); mx.w = fmaxf(mx.w, b.w);
    }
    float* gm = gfeat + (size_t)g * (2 * HCc);
    sum.x *= inv; sum.y *= inv; sum.z *= inv; sum.w *= inv;
    *(float4*)(gm + 4 * t) = sum;
    *(float4*)(gm + HCc + 4 * t) = mx;
}

// final MLP head: out = relu(relu(gfeat@W_fc + b_fc) @ W_out + b_out)
__global__ __launch_bounds__(128)
void head_kernel(const float* __restrict__ gfeat, const float* __restrict__ W_fc,
                 const float* __restrict__ b_fc, const float* __restrict__ W_out,
                 const float* __restrict__ b_out, float* __restrict__ out) {
    int g = blockIdx.x;
    int t = threadIdx.x;  // 128
    __shared__ float gf[2 * HCc];
    __shared__ float fc1[H2c];
    for (int i = t; i < 2 * HCc; i += 128) gf[i] = gfeat[(size_t)g * (2 * HCc) + i];
    __syncthreads();
    float a0 = 0.f, a1 = 0.f, a2 = 0.f, a3 = 0.f;
    for (int k = 0; k < 2 * HCc; k += 4) {
        a0 = fmaf(gf[k],     W_fc[(size_t)k * H2c + t], a0);
        a1 = fmaf(gf[k + 1], W_fc[(size_t)(k + 1) * H2c + t], a1);
        a2 = fmaf(gf[k + 2], W_fc[(size_t)(k + 2) * H2c + t], a2);
        a3 = fmaf(gf[k + 3], W_fc[(size_t)(k + 3) * H2c + t], a3);
    }
    fc1[t] = fmaxf(b_fc[t] + ((a0 + a1) + (a2 + a3)), 0.f);
    __syncthreads();
    if (t < OUTc) {
        float o = b_out[t];
        #pragma unroll 8
        for (int k = 0; k < H2c; ++k) o += fc1[k] * W_out[k * OUTc + t];
        out[g * OUTc + t] = fmaxf(o, 0.f);
    }
}

extern "C" void kernel_launch(void* const* d_in, const int* in_sizes, int n_in,
                              void* d_out, int out_size, void* d_ws, size_t ws_size,
                              hipStream_t stream) {
    (void)in_sizes; (void)n_in; (void)out_size; (void)ws_size;
    const float* x        = (const float*)d_in[0];
    const float* pe       = (const float*)d_in[1];
    const int*   eidx     = (const int*)d_in[2];
    const int*   batch    = (const int*)d_in[3];
    const float* fw       = (const float*)d_in[4];
    const float* W_pre    = (const float*)d_in[6];
    const float* b_pre    = (const float*)d_in[7];
    const float* W_l      = (const float*)d_in[8];
    const float* b_l      = (const float*)d_in[9];
    const float* W_r      = (const float*)d_in[10];
    const float* b_r      = (const float*)d_in[11];
    const float* att      = (const float*)d_in[12];
    const float* gat_bias = (const float*)d_in[13];
    const float* W_gcn    = (const float*)d_in[14];
    const float* b_gcn    = (const float*)d_in[15];
    const float* W_fc     = (const float*)d_in[16];
    const float* b_fc     = (const float*)d_in[17];
    const float* W_out    = (const float*)d_in[18];
    const float* b_out    = (const float*)d_in[19];
    float* out = (float*)d_out;

    // ---- workspace carving ----
    char* p = (char*)d_ws;
    auto alloc = [&](size_t bytes) {
        char* r = p;
        p += (bytes + 255) & ~(size_t)255;
        return r;
    };
    unsigned short* hh = (unsigned short*)alloc((size_t)Nn * Dd * 2 * 2);
    unsigned short* hl = hh + (size_t)Nn * Dd;
    float* bufA = (float*)alloc((size_t)Nn * HCc * 4);  // xl, later hg
    float* bufB = (float*)alloc((size_t)Nn * HCc * 4);  // xr, later g2
    float* bufC = (float*)alloc((size_t)Nn * HCc * 4);  // x splits, later g1 splits
    int*   cnt    = (int*)alloc((size_t)Nn * 4);
    int*   off    = (int*)alloc((size_t)(Nn + 1) * 4);
    int*   nxt    = (int*)alloc((size_t)Nn * 4);
    float* dinv   = (float*)alloc((size_t)Nn * 4);
    int*   elist  = (int*)alloc((size_t)ETot * 4);
    int*   starts = (int*)alloc((size_t)(Gg + 1) * 4);
    float* gfeat  = (float*)alloc((size_t)Gg * 2 * HCc * 4);
    int*   bsum   = (int*)alloc((size_t)NBLK * 4);
    float* pw     = (float*)alloc((size_t)Gg * PSL * 4);
    float* pmean  = (float*)alloc((size_t)Gg * PSL * HCc * 4);
    float* pmax   = (float*)alloc((size_t)Gg * PSL * HCc * 4);
    unsigned short* WpreTh = (unsigned short*)alloc((size_t)Ff * H1c * 2 * 2);
    unsigned short* WpreTl = WpreTh + (size_t)Ff * H1c;
    unsigned short* WlrTh  = (unsigned short*)alloc((size_t)Dd * 2 * HCc * 2 * 2);
    unsigned short* WlrTl  = WlrTh + (size_t)Dd * 2 * HCc;
    unsigned short* WgTh   = (unsigned short*)alloc((size_t)HCc * HCc * 2 * 2);
    unsigned short* WgTl   = WgTh + (size_t)HCc * HCc;

    // aliases (disjoint lifetimes within bufC)
    unsigned short* xh  = (unsigned short*)bufC;   // x splits: prep -> GEMM1
    unsigned short* xlo = xh + (size_t)Nn * Ff;
    unsigned short* g1h = (unsigned short*)bufC;   // g1 splits: fused agg -> GEMM4
    unsigned short* g1l = g1h + (size_t)Nn * HCc;

    // ---- CSR build ----
    hipMemsetAsync(cnt, 0, (size_t)Nn * 4, stream);
    count_kernel<<<(Ee + 255) / 256, 256, 0, stream>>>(eidx, cnt);
    scan1_kernel<<<NBLK, 256, 0, stream>>>(cnt, off, bsum);
    scan2_kernel<<<1, 64, 0, stream>>>(bsum);
    scan3_kernel<<<NBLK, 256, 0, stream>>>(cnt, off, nxt, dinv, bsum);
    scatter_kernel<<<(ETot + 255) / 256, 256, 0, stream>>>(eidx, nxt, elist);

    // ---- splits ----
    asplit_kernel<<<(Nn * Ff / 4 + 255) / 256, 256, 0, stream>>>(x, xh, xlo, Nn * Ff / 4);
    wsplit_kernel<<<(Ff * H1c + 255) / 256, 256, 0, stream>>>(W_pre, WpreTh, WpreTl, Ff, H1c);
    wsplit_kernel<<<(Dd * HCc + 255) / 256, 256, 0, stream>>>(W_l, WlrTh, WlrTl, Dd, HCc);
    wsplit_kernel<<<(Dd * HCc + 255) / 256, 256, 0, stream>>>(
        W_r, WlrTh + (size_t)HCc * Dd, WlrTl + (size_t)HCc * Dd, Dd, HCc);
    wsplit_kernel<<<(HCc * HCc + 255) / 256, 256, 0, stream>>>(W_gcn, WgTh, WgTl, HCc, HCc);

    // ---- GEMM1 (64x64 tile): h = relu(x@W_pre+b) -> h splits ----
    {
        dim3 grid((Nn + 63) / 64, (H1c + 63) / 64);
        gemm3_kernel<64, 64, 1><<<grid, 256, 0, stream>>>(
            xh, xlo, WpreTh, WpreTl, b_pre, nullptr, nullptr, nullptr, hh, hl,
            Nn, H1c, Ff, Ff, Dd, 1);
    }
    pe_copy_kernel<<<(Nn * PEc + 255) / 256, 256, 0, stream>>>(pe, hh, hl);

    // ---- merged GEMM2/3: [xl | xr] = h @ [W_l | W_r], cols<800 -> bufA else bufB ----
    {
        dim3 grid((Nn + 127) / 128, (2 * HCc + 127) / 128);
        gemm3_kernel<128, 128, 2><<<grid, 256, 0, stream>>>(
            hh, hl, WlrTh, WlrTl, b_l, b_r, bufA, bufB, nullptr, nullptr,
            Nn, 2 * HCc, Dd, Dd, HCc, 0);
    }

    // ---- FUSED GATv2 (single-read, 16-edge chunks) -> g1 (bufC) ----
    fused_gat_kernel<<<Nn, 256, 0, stream>>>(bufA, bufB, att, elist, off,
                                             gat_bias, g1h, g1l);

    // ---- GEMM4: hg = g1 @ W_gcn -> bufA (xl dead) ----
    {
        dim3 grid((Nn + 127) / 128, (HCc + 127) / 128);
        gemm3_kernel<128, 128, 0><<<grid, 256, 0, stream>>>(
            g1h, g1l, WgTh, WgTl, nullptr, nullptr, bufA, nullptr, nullptr, nullptr,
            Nn, HCc, HCc, HCc, HCc, 0);
    }
    // ---- GCN aggregate -> g2 (bufB, xr dead) ----
    gcn_kernel<<<Nn, 256, 0, stream>>>(bufA, dinv, elist, off, b_gcn, bufB);

    // ---- pooling (two-stage) + head ----
    bounds_kernel<<<1, 128, 0, stream>>>(batch, starts);
    {
        dim3 pg(Gg, PSL);
        pool1_kernel<<<pg, 256, 0, stream>>>(bufB, fw, starts, pw, pmean, pmax);
    }
    pool2_kernel<<<Gg, 256, 0, stream>>>(pw, pmean, pmax, gfeat);
    head_kernel<<<Gg, 128, 0, stream>>>(gfeat, W_fc, b_fc, W_out, b_out, out);
}

// Round 11
// 739.007 us; speedup vs baseline: 1.3336x; 1.0149x over previous
//
#include <hip/hip_runtime.h>
#include <hip/hip_bf16.h>

// Problem constants (fixed by reference)
#define Nn     20000
#define Ee     240000
#define Gg     64
#define Ff     768
#define H1c    128
#define PEc    32
#define Dd     160      // H1 + PE
#define HEADSc 5
#define HCc    800      // HEADS * D
#define H2c    128
#define OUTc   16
#define ETot   (Ee + Nn)  // edges + self loops = 260000
#define NEG_SLOPE_F 0.2f

typedef short bf16x8 __attribute__((ext_vector_type(8)));
typedef float f32x4 __attribute__((ext_vector_type(4)));
typedef float f32x16 __attribute__((ext_vector_type(16)));
typedef unsigned int u32;

// ---- bf16 split helpers (round-to-nearest-even) ----
__device__ __forceinline__ unsigned short bf_hi_rn(float v) {
    unsigned int u = __float_as_uint(v);
    return (unsigned short)((u + 0x7FFFu + ((u >> 16) & 1u)) >> 16);
}
__device__ __forceinline__ void bsplit(float v, unsigned short& h, unsigned short& l) {
    unsigned short hh = bf_hi_rn(v);
    float hf = __uint_as_float(((unsigned int)hh) << 16);
    l = bf_hi_rn(v - hf);
    h = hh;
}

// async global->LDS, 16 B per lane; LDS dest = wave-uniform base + lane*16
__device__ __forceinline__ void gl_lds16(const unsigned short* g, unsigned short* l) {
    __builtin_amdgcn_global_load_lds(
        (const __attribute__((address_space(1))) u32*)g,
        (__attribute__((address_space(3))) u32*)l, 16, 0, 0);
}

// ---------------------------------------------------------------------------
// Split fp32 array -> bf16 hi/lo arrays (same layout), vectorized by 4
// ---------------------------------------------------------------------------
__global__ void asplit_kernel(const float* __restrict__ A, unsigned short* __restrict__ Ah,
                              unsigned short* __restrict__ Al, int total4) {
    int i = blockIdx.x * 256 + threadIdx.x;
    if (i < total4) {
        float4 v = ((const float4*)A)[i];
        ushort4 h4, l4;
        bsplit(v.x, h4.x, l4.x);
        bsplit(v.y, h4.y, l4.y);
        bsplit(v.z, h4.z, l4.z);
        bsplit(v.w, h4.w, l4.w);
        ((ushort4*)Ah)[i] = h4;
        ((ushort4*)Al)[i] = l4;
    }
}

// Weight transpose + split: W[K][N] fp32 -> Wh/Wl[N][K] bf16
__global__ void wsplit_kernel(const float* __restrict__ W, unsigned short* __restrict__ Wh,
                              unsigned short* __restrict__ Wl, int K, int N) {
    int i = blockIdx.x * 256 + threadIdx.x;
    if (i < K * N) {
        int k = i / N, n = i % N;
        unsigned short h, l;
        bsplit(W[i], h, l);
        Wh[(size_t)n * K + k] = h;
        Wl[(size_t)n * K + k] = l;
    }
}

// ---------------------------------------------------------------------------
// bf16x3 MFMA GEMM on v_mfma_f32_32x32x16_bf16 with XOR-swizzled LDS and
// XCD-aware 1D block remap: lin -> xcd=lin&7, loc=lin>>3;
// m-tile = xcd*mPerX + loc/numN, n-tile = loc%numN.  The numN blocks sharing
// one A-tile land on the SAME XCD, dispatch-adjacent -> A-tile L2-resident.
// ---------------------------------------------------------------------------
#define KCHUNK 32

template<int ROWS>
__device__ __forceinline__ void stage_tile(const unsigned short* __restrict__ gsrc, int ld,
                                           int row0, int maxRow, int k0,
                                           unsigned short* lbuf, int wave, int lane) {
    #pragma unroll
    for (int p = 0; p < ROWS / 64; ++p) {
        int rb = wave * 16 + p * 64;
        int r = rb + (lane >> 2);
        int gr = min(row0 + r, maxRow);
        int ksub = (lane & 3) ^ ((r >> 1) & 3);   // source sub-block swizzle
        const unsigned short* g = gsrc + (size_t)gr * ld + k0 + ksub * 8;
        gl_lds16(g, lbuf + rb * 32);
    }
}

template<int BM, int BN, int OUT_MODE>
__global__ __launch_bounds__(256)
void gemm3_kernel(const unsigned short* __restrict__ Ah, const unsigned short* __restrict__ Al,
                  const unsigned short* __restrict__ Bh, const unsigned short* __restrict__ Bl,
                  const float* __restrict__ bias, const float* __restrict__ bias2,
                  float* __restrict__ C, float* __restrict__ C2,
                  unsigned short* __restrict__ Ch, unsigned short* __restrict__ Cl,
                  int M, int N, int K, int lda, int ldc, int relu,
                  int numM, int numN, int mPerX) {
    constexpr int TM = BM / 64;   // 32x32 tiles per wave in m
    constexpr int TN = BN / 64;
    __shared__ __attribute__((aligned(16))) unsigned short As_h[BM * 32];
    __shared__ __attribute__((aligned(16))) unsigned short As_l[BM * 32];
    __shared__ __attribute__((aligned(16))) unsigned short Bs_h[BN * 32];
    __shared__ __attribute__((aligned(16))) unsigned short Bs_l[BN * 32];

    // XCD-aware remap (see header comment)
    int lin = blockIdx.x;
    int xcd = lin & 7, loc = lin >> 3;
    int mi = xcd * mPerX + loc / numN;
    int ni = loc % numN;
    if (mi >= numM) return;
    int m0 = mi * BM, n0 = ni * BN;

    int tid = threadIdx.x;
    int wave = tid >> 6, lane = tid & 63;
    int wm = (wave >> 1) * (32 * TM);
    int wn = (wave & 1) * (32 * TN);
    int fr = lane & 31;            // m (or n) within 32-tile
    int subhi = lane >> 5;         // k sub-block bit 0

    f32x16 acc[TM][TN] = {};

    for (int k0 = 0; k0 < K; k0 += KCHUNK) {
        stage_tile<BM>(Ah, lda, m0, M - 1, k0, As_h, wave, lane);
        stage_tile<BM>(Al, lda, m0, M - 1, k0, As_l, wave, lane);
        stage_tile<BN>(Bh, K,   n0, N - 1, k0, Bs_h, wave, lane);
        stage_tile<BN>(Bl, K,   n0, N - 1, k0, Bs_l, wave, lane);
        __syncthreads();

        bf16x8 a_h[TM][2], a_l[TM][2], b_h[TN][2], b_l[TN][2];
        #pragma unroll
        for (int i = 0; i < TM; ++i) {
            int ar = wm + i * 32 + fr;
            int asw = (ar >> 1) & 3;
            #pragma unroll
            for (int s = 0; s < 2; ++s) {
                int lsub = ((s << 1) | subhi) ^ asw;
                a_h[i][s] = *(const bf16x8*)&As_h[ar * 32 + lsub * 8];
                a_l[i][s] = *(const bf16x8*)&As_l[ar * 32 + lsub * 8];
            }
        }
        #pragma unroll
        for (int j = 0; j < TN; ++j) {
            int br = wn + j * 32 + fr;
            int bsw = (br >> 1) & 3;
            #pragma unroll
            for (int s = 0; s < 2; ++s) {
                int lsub = ((s << 1) | subhi) ^ bsw;
                b_h[j][s] = *(const bf16x8*)&Bs_h[br * 32 + lsub * 8];
                b_l[j][s] = *(const bf16x8*)&Bs_l[br * 32 + lsub * 8];
            }
        }
        #pragma unroll
        for (int j = 0; j < TN; ++j) {
            #pragma unroll
            for (int i = 0; i < TM; ++i) {
                #pragma unroll
                for (int s = 0; s < 2; ++s) {
                    acc[i][j] = __builtin_amdgcn_mfma_f32_32x32x16_bf16(a_h[i][s], b_h[j][s], acc[i][j], 0, 0, 0);
                    acc[i][j] = __builtin_amdgcn_mfma_f32_32x32x16_bf16(a_h[i][s], b_l[j][s], acc[i][j], 0, 0, 0);
                    acc[i][j] = __builtin_amdgcn_mfma_f32_32x32x16_bf16(a_l[i][s], b_h[j][s], acc[i][j], 0, 0, 0);
                }
            }
        }
        __syncthreads();
    }

    // epilogue: C/D 32x32 layout col=lane&31, row=(reg&3)+8*(reg>>2)+4*(lane>>5)
    int cc = lane & 31;
    int rq = 4 * (lane >> 5);
    #pragma unroll
    for (int i = 0; i < TM; ++i) {
        #pragma unroll
        for (int j = 0; j < TN; ++j) {
            int c = n0 + wn + j * 32 + cc;
            if (c >= N) continue;
            float bv;
            if (OUT_MODE == 2) bv = (c < HCc) ? bias[c] : bias2[c - HCc];
            else bv = bias ? bias[c] : 0.f;
            #pragma unroll
            for (int reg = 0; reg < 16; ++reg) {
                int r = m0 + wm + i * 32 + (reg & 3) + 8 * (reg >> 2) + rq;
                if (r >= M) continue;
                float v = acc[i][j][reg] + bv;
                if (relu) v = fmaxf(v, 0.f);
                if (OUT_MODE == 0) {
                    C[(size_t)r * ldc + c] = v;
                } else if (OUT_MODE == 2) {
                    if (c < HCc) C[(size_t)r * HCc + c] = v;
                    else         C2[(size_t)r * HCc + (c - HCc)] = v;
                } else {
                    unsigned short hh, ll;
                    bsplit(v, hh, ll);
                    Ch[(size_t)r * ldc + c] = hh;
                    Cl[(size_t)r * ldc + c] = ll;
                }
            }
        }
    }
}

// copy pe_enc into h splits cols [128:160)
__global__ void pe_copy_kernel(const float* __restrict__ pe, unsigned short* __restrict__ hh,
                               unsigned short* __restrict__ hl) {
    int i = blockIdx.x * 256 + threadIdx.x;
    if (i < Nn * PEc) {
        int n = i / PEc, j = i % PEc;
        unsigned short h, l;
        bsplit(pe[i], h, l);
        hh[(size_t)n * Dd + H1c + j] = h;
        hl[(size_t)n * Dd + H1c + j] = l;
    }
}

// count in-degree (real edges only)
__global__ void count_kernel(const int* __restrict__ eidx, int* __restrict__ cnt) {
    int e = blockIdx.x * 256 + threadIdx.x;
    if (e < Ee) atomicAdd(&cnt[eidx[Ee + e]], 1);
}

// ---- multi-block exclusive scan over (cnt[i]+1) ----
#define NBLK 79  // ceil(20000/256)
__global__ void scan1_kernel(const int* __restrict__ cnt, int* __restrict__ off,
                             int* __restrict__ bsum) {
    __shared__ int sh[256];
    int t = threadIdx.x, i = blockIdx.x * 256 + t;
    int v = (i < Nn) ? (cnt[i] + 1) : 0;
    sh[t] = v;
    __syncthreads();
    for (int ofs = 1; ofs < 256; ofs <<= 1) {
        int add = (t >= ofs) ? sh[t - ofs] : 0;
        __syncthreads();
        sh[t] += add;
        __syncthreads();
    }
    if (i < Nn) off[i] = sh[t] - v;
    if (t == 255) bsum[blockIdx.x] = sh[255];
}
__global__ void scan2_kernel(int* __restrict__ bsum) {
    if (threadIdx.x == 0) {
        int acc = 0;
        for (int b = 0; b < NBLK; ++b) { int v = bsum[b]; bsum[b] = acc; acc += v; }
    }
}
__global__ void scan3_kernel(const int* __restrict__ cnt, int* __restrict__ off,
                             int* __restrict__ nxt, float* __restrict__ dinv,
                             const int* __restrict__ bsum) {
    int i = blockIdx.x * 256 + threadIdx.x;
    if (i < Nn) {
        int o = off[i] + bsum[blockIdx.x];
        off[i] = o;
        nxt[i] = o;
        dinv[i] = rsqrtf((float)(cnt[i] + 1));
    }
    if (i == 0) off[Nn] = ETot;
}

// scatter edges (and self loops) into CSR by dst
__global__ void scatter_kernel(const int* __restrict__ eidx, int* __restrict__ nxt,
                               int* __restrict__ elist) {
    int e = blockIdx.x * 256 + threadIdx.x;
    if (e < ETot) {
        int s, d;
        if (e < Ee) { s = eidx[e]; d = eidx[Ee + e]; }
        else        { s = e - Ee; d = s; }
        int slot = atomicAdd(&nxt[d], 1);
        elist[slot] = s;
    }
}

// ---------------------------------------------------------------------------
// FUSED GATv2, single-read register version (16-edge chunks, float4 reduce).
// ---------------------------------------------------------------------------
#define FCH 16
__global__ __launch_bounds__(256)
void fused_gat_kernel(const float* __restrict__ xl, const float* __restrict__ xr,
                      const float* __restrict__ att, const int* __restrict__ elist,
                      const int* __restrict__ off, const float* __restrict__ gat_bias,
                      unsigned short* __restrict__ g1h, unsigned short* __restrict__ g1l) {
    int d = blockIdx.x;
    int t = threadIdx.x;
    __shared__ __attribute__((aligned(16))) float sh_red[FCH][200];
    __shared__ float sh_sc[FCH][HEADSc];
    __shared__ float sh_w[FCH][HEADSc];
    __shared__ float sh_scale[HEADSc], sh_m[HEADSc], sh_den[HEADSc];
    __shared__ int sh_src[FCH];
    int e0 = off[d], e1 = off[d + 1];
    int cnt = e1 - e0;
    bool act = t < 200;
    int hd = act ? (t / 40) : 0;
    float4 vr = {0.f, 0.f, 0.f, 0.f}, va = {0.f, 0.f, 0.f, 0.f};
    if (act) {
        vr = ((const float4*)(xr + (size_t)d * HCc))[t];
        va = ((const float4*)att)[t];
    }
    if (t < HEADSc) { sh_m[t] = -1e30f; sh_den[t] = 0.f; }
    float4 acc = {0.f, 0.f, 0.f, 0.f};

    for (int base = 0; base < cnt; base += FCH) {
        int nc = min(FCH, cnt - base);
        if (t < FCH) sh_src[t] = elist[e0 + base + min(t, nc - 1)];
        __syncthreads();   // src visible (also fences prev chunk's sh_w reads)
        float4 vl[FCH];
        if (act) {
            #pragma unroll
            for (int e = 0; e < FCH; ++e)
                vl[e] = ((const float4*)(xl + (size_t)sh_src[e] * HCc))[t];
            #pragma unroll
            for (int e = 0; e < FCH; ++e) {
                float p = 0.f, m, lm;
                m = vl[e].x + vr.x; lm = fmaxf(m, 0.2f * m); p = fmaf(lm, va.x, p);
                m = vl[e].y + vr.y; lm = fmaxf(m, 0.2f * m); p = fmaf(lm, va.y, p);
                m = vl[e].z + vr.z; lm = fmaxf(m, 0.2f * m); p = fmaf(lm, va.z, p);
                m = vl[e].w + vr.w; lm = fmaxf(m, 0.2f * m); p = fmaf(lm, va.w, p);
                sh_red[e][t] = p;
            }
        }
        __syncthreads();   // partials visible
        if (t < 40) {      // two (edge,head) pairs per thread — all wave 0
            int e = t & 7, h = t >> 3;
            const float4* p0 = (const float4*)&sh_red[e][h * 40];
            const float4* p1 = (const float4*)&sh_red[e + 8][h * 40];
            float4 s4a = {0.f, 0.f, 0.f, 0.f}, s4b = {0.f, 0.f, 0.f, 0.f};
            #pragma unroll
            for (int k = 0; k < 10; ++k) {
                float4 u = p0[k], w = p1[k];
                s4a.x += u.x; s4a.y += u.y; s4a.z += u.z; s4a.w += u.w;
                s4b.x += w.x; s4b.y += w.y; s4b.z += w.z; s4b.w += w.w;
            }
            float s0 = (s4a.x + s4a.y) + (s4a.z + s4a.w);
            float s1 = (s4b.x + s4b.y) + (s4b.z + s4b.w);
            sh_sc[e][h]     = (e < nc)     ? s0 : -1e30f;
            sh_sc[e + 8][h] = (e + 8 < nc) ? s1 : -1e30f;
        }
        if (t < HEADSc) {  // same wave: LDS ops stay ordered
            float mo = sh_m[t];
            float mn = mo;
            #pragma unroll
            for (int e = 0; e < FCH; ++e) mn = fmaxf(mn, sh_sc[e][t]);
            float sc = __expf(mo - mn);
            float den = sh_den[t] * sc;
            #pragma unroll
            for (int e = 0; e < FCH; ++e) {
                float w = __expf(sh_sc[e][t] - mn);
                sh_w[e][t] = w;
                den += w;
            }
            sh_den[t] = den;
            sh_m[t] = mn;
            sh_scale[t] = sc;
        }
        __syncthreads();   // weights visible
        if (act) {
            float sc = sh_scale[hd];
            acc.x *= sc; acc.y *= sc; acc.z *= sc; acc.w *= sc;
            #pragma unroll
            for (int e = 0; e < FCH; ++e) {
                float w = sh_w[e][hd];   // 0 for invalid tail edges
                acc.x = fmaf(w, vl[e].x, acc.x);
                acc.y = fmaf(w, vl[e].y, acc.y);
                acc.z = fmaf(w, vl[e].z, acc.z);
                acc.w = fmaf(w, vl[e].w, acc.w);
            }
        }
    }
    if (act) {
        float inv = 1.f / sh_den[hd];
        float4 bv = ((const float4*)gat_bias)[t];
        ushort4 oh, ol;
        float v;
        v = fmaxf(fmaf(acc.x, inv, bv.x), 0.f); bsplit(v, oh.x, ol.x);
        v = fmaxf(fmaf(acc.y, inv, bv.y), 0.f); bsplit(v, oh.y, ol.y);
        v = fmaxf(fmaf(acc.z, inv, bv.z), 0.f); bsplit(v, oh.z, ol.z);
        v = fmaxf(fmaf(acc.w, inv, bv.w), 0.f); bsplit(v, oh.w, ol.w);
        *(ushort4*)(g1h + (size_t)d * HCc + 4 * t) = oh;
        *(ushort4*)(g1l + (size_t)d * HCc + 4 * t) = ol;
    }
}

// GCN aggregate, register-batched: g2[d] = relu(dinv[d]*sum dinv[src]*hg[src]+b)
#define GCH 16
__global__ __launch_bounds__(256)
void gcn_kernel(const float* __restrict__ hg, const float* __restrict__ dinv,
                const int* __restrict__ elist, const int* __restrict__ off,
                const float* __restrict__ b_gcn, float* __restrict__ g2) {
    int d = blockIdx.x;
    int t = threadIdx.x;
    __shared__ int src_s[GCH];
    __shared__ float w_s[GCH];
    int e0 = off[d], e1 = off[d + 1];
    int cnt = e1 - e0;
    float di = dinv[d];
    bool act = t < 200;
    float4 acc = {0.f, 0.f, 0.f, 0.f};
    for (int base = 0; base < cnt; base += GCH) {
        int nc = min(GCH, cnt - base);
        if (t < GCH) {
            int s = elist[e0 + base + min(t, nc - 1)];
            src_s[t] = s;
            w_s[t] = (t < nc) ? dinv[s] : 0.f;
        }
        __syncthreads();
        if (act) {
            float4 vl[GCH];
            #pragma unroll
            for (int e = 0; e < GCH; ++e)
                vl[e] = ((const float4*)(hg + (size_t)src_s[e] * HCc))[t];
            #pragma unroll
            for (int e = 0; e < GCH; ++e) {
                float w = w_s[e];
                acc.x = fmaf(w, vl[e].x, acc.x);
                acc.y = fmaf(w, vl[e].y, acc.y);
                acc.z = fmaf(w, vl[e].z, acc.z);
                acc.w = fmaf(w, vl[e].w, acc.w);
            }
        }
        __syncthreads();
    }
    if (act) {
        float4 bv = ((const float4*)b_gcn)[t];
        float4 o;
        o.x = fmaxf(acc.x * di + bv.x, 0.f);
        o.y = fmaxf(acc.y * di + bv.y, 0.f);
        o.z = fmaxf(acc.z * di + bv.z, 0.f);
        o.w = fmaxf(acc.w * di + bv.w, 0.f);
        *(float4*)(g2 + (size_t)d * HCc + 4 * t) = o;
    }
}

// graph boundaries in sorted batch (lower bound per graph)
__global__ void bounds_kernel(const int* __restrict__ batch, int* __restrict__ starts) {
    int g = threadIdx.x;
    if (g <= Gg) {
        if (g == Gg) { starts[Gg] = Nn; return; }
        int lo = 0, hi = Nn;
        while (lo < hi) {
            int mid = (lo + hi) >> 1;
            if (batch[mid] < g) lo = mid + 1; else hi = mid;
        }
        starts[g] = lo;
    }
}

// ---- two-stage pool: node-sliced partials, then combine ----
#define PSL 4
__global__ __launch_bounds__(256)
void pool1_kernel(const float* __restrict__ g2, const float* __restrict__ fw,
                  const int* __restrict__ starts, float* __restrict__ pw,
                  float* __restrict__ pmean, float* __restrict__ pmax) {
    int g = blockIdx.x, s = blockIdx.y, t = threadIdx.x;
    int n0 = starts[g], n1 = starts[g + 1];
    int len = n1 - n0;
    int q0 = n0 + (int)(((long long)len * s) / PSL);
    int q1 = n0 + (int)(((long long)len * (s + 1)) / PSL);
    __shared__ float red[256];
    float wsum = 0.f;
    for (int n = q0 + t; n < q1; n += 256) wsum += fw[n];
    red[t] = wsum;
    __syncthreads();
    for (int ofs = 128; ofs > 0; ofs >>= 1) {
        if (t < ofs) red[t] += red[t + ofs];
        __syncthreads();
    }
    if (t == 0) pw[g * PSL + s] = red[0];
    if (t < 200) {
        float4 sum = {0.f, 0.f, 0.f, 0.f};
        float4 mx = {0.f, 0.f, 0.f, 0.f};
        for (int n = q0; n < q1; ++n) {
            float w = fw[n];
            float4 v = ((const float4*)(g2 + (size_t)n * HCc))[t];
            sum.x = fmaf(w, v.x, sum.x); sum.y = fmaf(w, v.y, sum.y);
            sum.z = fmaf(w, v.z, sum.z); sum.w = fmaf(w, v.w, sum.w);
            mx.x = fmaxf(mx.x, v.x); mx.y = fmaxf(mx.y, v.y);
            mx.z = fmaxf(mx.z, v.z); mx.w = fmaxf(mx.w, v.w);
        }
        size_t o = ((size_t)g * PSL + s) * HCc + 4 * t;
        *(float4*)(pmean + o) = sum;
        *(float4*)(pmax + o) = mx;
    }
}
__global__ __launch_bounds__(256)
void pool2_kernel(const float* __restrict__ pw, const float* __restrict__ pmean,
                  const float* __restrict__ pmax, float* __restrict__ gfeat) {
    int g = blockIdx.x, t = threadIdx.x;
    if (t >= 200) return;
    float wsg = 0.f;
    #pragma unroll
    for (int s = 0; s < PSL; ++s) wsg += pw[g * PSL + s];
    wsg = fmaxf(wsg, 1e-6f);
    float inv = 1.f / wsg;
    float4 sum = {0.f, 0.f, 0.f, 0.f};
    float4 mx = {0.f, 0.f, 0.f, 0.f};
    #pragma unroll
    for (int s = 0; s < PSL; ++s) {
        size_t o = ((size_t)g * PSL + s) * HCc + 4 * t;
        float4 a = *(const float4*)(pmean + o);
        float4 b = *(const float4*)(pmax + o);
        sum.x += a.x; sum.y += a.y; sum.z += a.z; sum.w += a.w;
        mx.x = fmaxf(mx.x, b.x); mx.y = fmaxf(mx.y, b.y);
        mx.z = fmaxf(mx.z, b.z); mx.w = fmaxf(mx.w, b.w);
    }
    float* gm = gfeat + (size_t)g * (2 * HCc);
    sum.x *= inv; sum.y *= inv; sum.z *= inv; sum.w *= inv;
    *(float4*)(gm + 4 * t) = sum;
    *(float4*)(gm + HCc + 4 * t) = mx;
}

// final MLP head: out = relu(relu(gfeat@W_fc + b_fc) @ W_out + b_out)
__global__ __launch_bounds__(128)
void head_kernel(const float* __restrict__ gfeat, const float* __restrict__ W_fc,
                 const float* __restrict__ b_fc, const float* __restrict__ W_out,
                 const float* __restrict__ b_out, float* __restrict__ out) {
    int g = blockIdx.x;
    int t = threadIdx.x;  // 128
    __shared__ float gf[2 * HCc];
    __shared__ float fc1[H2c];
    for (int i = t; i < 2 * HCc; i += 128) gf[i] = gfeat[(size_t)g * (2 * HCc) + i];
    __syncthreads();
    float a0 = 0.f, a1 = 0.f, a2 = 0.f, a3 = 0.f;
    for (int k = 0; k < 2 * HCc; k += 4) {
        a0 = fmaf(gf[k],     W_fc[(size_t)k * H2c + t], a0);
        a1 = fmaf(gf[k + 1], W_fc[(size_t)(k + 1) * H2c + t], a1);
        a2 = fmaf(gf[k + 2], W_fc[(size_t)(k + 2) * H2c + t], a2);
        a3 = fmaf(gf[k + 3], W_fc[(size_t)(k + 3) * H2c + t], a3);
    }
    fc1[t] = fmaxf(b_fc[t] + ((a0 + a1) + (a2 + a3)), 0.f);
    __syncthreads();
    if (t < OUTc) {
        float o = b_out[t];
        #pragma unroll 8
        for (int k = 0; k < H2c; ++k) o += fc1[k] * W_out[k * OUTc + t];
        out[g * OUTc + t] = fmaxf(o, 0.f);
    }
}

extern "C" void kernel_launch(void* const* d_in, const int* in_sizes, int n_in,
                              void* d_out, int out_size, void* d_ws, size_t ws_size,
                              hipStream_t stream) {
    (void)in_sizes; (void)n_in; (void)out_size; (void)ws_size;
    const float* x        = (const float*)d_in[0];
    const float* pe       = (const float*)d_in[1];
    const int*   eidx     = (const int*)d_in[2];
    const int*   batch    = (const int*)d_in[3];
    const float* fw       = (const float*)d_in[4];
    const float* W_pre    = (const float*)d_in[6];
    const float* b_pre    = (const float*)d_in[7];
    const float* W_l      = (const float*)d_in[8];
    const float* b_l      = (const float*)d_in[9];
    const float* W_r      = (const float*)d_in[10];
    const float* b_r      = (const float*)d_in[11];
    const float* att      = (const float*)d_in[12];
    const float* gat_bias = (const float*)d_in[13];
    const float* W_gcn    = (const float*)d_in[14];
    const float* b_gcn    = (const float*)d_in[15];
    const float* W_fc     = (const float*)d_in[16];
    const float* b_fc     = (const float*)d_in[17];
    const float* W_out    = (const float*)d_in[18];
    const float* b_out    = (const float*)d_in[19];
    float* out = (float*)d_out;

    // ---- workspace carving ----
    char* p = (char*)d_ws;
    auto alloc = [&](size_t bytes) {
        char* r = p;
        p += (bytes + 255) & ~(size_t)255;
        return r;
    };
    unsigned short* hh = (unsigned short*)alloc((size_t)Nn * Dd * 2 * 2);
    unsigned short* hl = hh + (size_t)Nn * Dd;
    float* bufA = (float*)alloc((size_t)Nn * HCc * 4);  // xl, later hg
    float* bufB = (float*)alloc((size_t)Nn * HCc * 4);  // xr, later g2
    float* bufC = (float*)alloc((size_t)Nn * HCc * 4);  // x splits, later g1 splits
    int*   cnt    = (int*)alloc((size_t)Nn * 4);
    int*   off    = (int*)alloc((size_t)(Nn + 1) * 4);
    int*   nxt    = (int*)alloc((size_t)Nn * 4);
    float* dinv   = (float*)alloc((size_t)Nn * 4);
    int*   elist  = (int*)alloc((size_t)ETot * 4);
    int*   starts = (int*)alloc((size_t)(Gg + 1) * 4);
    float* gfeat  = (float*)alloc((size_t)Gg * 2 * HCc * 4);
    int*   bsum   = (int*)alloc((size_t)NBLK * 4);
    float* pw     = (float*)alloc((size_t)Gg * PSL * 4);
    float* pmean  = (float*)alloc((size_t)Gg * PSL * HCc * 4);
    float* pmax   = (float*)alloc((size_t)Gg * PSL * HCc * 4);
    unsigned short* WpreTh = (unsigned short*)alloc((size_t)Ff * H1c * 2 * 2);
    unsigned short* WpreTl = WpreTh + (size_t)Ff * H1c;
    unsigned short* WlrTh  = (unsigned short*)alloc((size_t)Dd * 2 * HCc * 2 * 2);
    unsigned short* WlrTl  = WlrTh + (size_t)Dd * 2 * HCc;
    unsigned short* WgTh   = (unsigned short*)alloc((size_t)HCc * HCc * 2 * 2);
    unsigned short* WgTl   = WgTh + (size_t)HCc * HCc;

    // aliases (disjoint lifetimes within bufC)
    unsigned short* xh  = (unsigned short*)bufC;   // x splits: prep -> GEMM1
    unsigned short* xlo = xh + (size_t)Nn * Ff;
    unsigned short* g1h = (unsigned short*)bufC;   // g1 splits: fused agg -> GEMM4
    unsigned short* g1l = g1h + (size_t)Nn * HCc;

    // ---- CSR build ----
    hipMemsetAsync(cnt, 0, (size_t)Nn * 4, stream);
    count_kernel<<<(Ee + 255) / 256, 256, 0, stream>>>(eidx, cnt);
    scan1_kernel<<<NBLK, 256, 0, stream>>>(cnt, off, bsum);
    scan2_kernel<<<1, 64, 0, stream>>>(bsum);
    scan3_kernel<<<NBLK, 256, 0, stream>>>(cnt, off, nxt, dinv, bsum);
    scatter_kernel<<<(ETot + 255) / 256, 256, 0, stream>>>(eidx, nxt, elist);

    // ---- splits ----
    asplit_kernel<<<(Nn * Ff / 4 + 255) / 256, 256, 0, stream>>>(x, xh, xlo, Nn * Ff / 4);
    wsplit_kernel<<<(Ff * H1c + 255) / 256, 256, 0, stream>>>(W_pre, WpreTh, WpreTl, Ff, H1c);
    wsplit_kernel<<<(Dd * HCc + 255) / 256, 256, 0, stream>>>(W_l, WlrTh, WlrTl, Dd, HCc);
    wsplit_kernel<<<(Dd * HCc + 255) / 256, 256, 0, stream>>>(
        W_r, WlrTh + (size_t)HCc * Dd, WlrTl + (size_t)HCc * Dd, Dd, HCc);
    wsplit_kernel<<<(HCc * HCc + 255) / 256, 256, 0, stream>>>(W_gcn, WgTh, WgTl, HCc, HCc);

    // ---- GEMM1 (64x64 tile): h = relu(x@W_pre+b) -> h splits ----
    {
        // numM=313 m-tiles, numN=2 n-tiles, mPerX=40 -> grid 8*40*2=640
        gemm3_kernel<64, 64, 1><<<640, 256, 0, stream>>>(
            xh, xlo, WpreTh, WpreTl, b_pre, nullptr, nullptr, nullptr, hh, hl,
            Nn, H1c, Ff, Ff, Dd, 1, 313, 2, 40);
    }
    pe_copy_kernel<<<(Nn * PEc + 255) / 256, 256, 0, stream>>>(pe, hh, hl);

    // ---- merged GEMM2/3: [xl | xr] = h @ [W_l | W_r], cols<800 -> bufA else bufB ----
    {
        // numM=157, numN=13, mPerX=20 -> grid 8*20*13=2080
        gemm3_kernel<128, 128, 2><<<2080, 256, 0, stream>>>(
            hh, hl, WlrTh, WlrTl, b_l, b_r, bufA, bufB, nullptr, nullptr,
            Nn, 2 * HCc, Dd, Dd, HCc, 0, 157, 13, 20);
    }

    // ---- FUSED GATv2 (single-read, 16-edge chunks) -> g1 (bufC) ----
    fused_gat_kernel<<<Nn, 256, 0, stream>>>(bufA, bufB, att, elist, off,
                                             gat_bias, g1h, g1l);

    // ---- GEMM4: hg = g1 @ W_gcn -> bufA (xl dead) ----
    {
        // numM=157, numN=7, mPerX=20 -> grid 8*20*7=1120
        gemm3_kernel<128, 128, 0><<<1120, 256, 0, stream>>>(
            g1h, g1l, WgTh, WgTl, nullptr, nullptr, bufA, nullptr, nullptr, nullptr,
            Nn, HCc, HCc, HCc, HCc, 0, 157, 7, 20);
    }
    // ---- GCN aggregate -> g2 (bufB, xr dead) ----
    gcn_kernel<<<Nn, 256, 0, stream>>>(bufA, dinv, elist, off, b_gcn, bufB);

    // ---- pooling (two-stage) + head ----
    bounds_kernel<<<1, 128, 0, stream>>>(batch, starts);
    {
        dim3 pg(Gg, PSL);
        pool1_kernel<<<pg, 256, 0, stream>>>(bufB, fw, starts, pw, pmean, pmax);
    }
    pool2_kernel<<<Gg, 256, 0, stream>>>(pw, pmean, pmax, gfeat);
    head_kernel<<<Gg, 128, 0, stream>>>(gfeat, W_fc, b_fc, W_out, b_out, out);
}